// Round 6
// baseline (338.000 us; speedup 1.0000x reference)
//
#include <hip/hip_runtime.h>
#include <hip/hip_bf16.h>
#include <hip/hip_fp16.h>

typedef _Float16 half8 __attribute__((ext_vector_type(8)));
typedef _Float16 half4 __attribute__((ext_vector_type(4)));
typedef float f32x4 __attribute__((ext_vector_type(4)));
typedef unsigned int u32;

#define S_LEN 2048
#define HID_DIM 4096
#define N_HEADS 32
#define N_KV 8
#define HEAD_DIM 128
#define SCALE_QK 0.08838834764831845f

// ---------- async global->LDS (16B per lane, wave-uniform LDS base) ----------
__device__ __forceinline__ void async16(void* lds, const void* gptr) {
  __builtin_amdgcn_global_load_lds(
      (const __attribute__((address_space(1))) u32*)gptr,
      (__attribute__((address_space(3))) u32*)lds, 16, 0, 0);
}

// ---------- f32 -> f16 convert (vectorized) ----------
__global__ void conv_f32_f16(const float* __restrict__ src, _Float16* __restrict__ dst, int n4) {
  int i = blockIdx.x * 256 + threadIdx.x;
  if (i < n4) {
    float4 v = ((const float4*)src)[i];
    half4 h;
    h[0] = (_Float16)v.x; h[1] = (_Float16)v.y; h[2] = (_Float16)v.z; h[3] = (_Float16)v.w;
    ((half4*)dst)[i] = h;
  }
}

// ---------- transpose f32 [R][C] -> f16 [C][R], 64(R)x32(C) tiles, 128B writes ----------
__global__ void transpose_f32_f16(const float* __restrict__ src, _Float16* __restrict__ dst,
                                  int R, int C) {
  __shared__ _Float16 tile[64][33];
  int bx = blockIdx.x;  // over C/32
  int by = blockIdx.y;  // over R/64
  int x = threadIdx.x, y = threadIdx.y;  // (32,8)
#pragma unroll
  for (int k = 0; k < 8; k++)
    tile[y + 8 * k][x] = (_Float16)src[(long)(by * 64 + y + 8 * k) * C + bx * 32 + x];
  __syncthreads();
  int tid = y * 32 + x;
  int r = tid & 63;
  int cb = tid >> 6;
#pragma unroll
  for (int w = 0; w < 8; w++) {
    int c = w * 4 + cb;
    dst[(long)(bx * 32 + c) * R + by * 64 + r] = tile[r][c];
  }
}

// ---------- RoPE in place on frag-tiled [h][s16][d/32][slot] layout (K only) ----------
template <int NHEADS>
__global__ void rope_tiled(_Float16* __restrict__ t, const float* __restrict__ cosb,
                           const float* __restrict__ sinb) {
  int idx = blockIdx.x * 256 + threadIdx.x;  // NHEADS * 2048 * 8
  int slo = idx & 15;
  int d8 = (idx >> 4) & 7;
  int h = (idx >> 7) % NHEADS;
  int s16 = idx / (128 * NHEADS);
  int s = s16 * 16 + slo;
  int d0 = d8 * 8;
  long c0 = (long)(h * 128 + s16) * 4;
  long base = (c0 + (d0 >> 5)) * 512 + ((d0 >> 3) & 3) * 128 + slo * 8;
  half8 a = *(half8*)(t + base);
  half8 b = *(half8*)(t + base + 1024);  // d0+64 -> chunk+2
  const float* cp = cosb + s * 128 + d0;
  const float* sp = sinb + s * 128 + d0;
  half8 olo, ohi;
#pragma unroll
  for (int j = 0; j < 8; j++) {
    float c = cp[j], sn = sp[j];
    float av = (float)a[j], bv = (float)b[j];
    olo[j] = (_Float16)(av * c - bv * sn);
    ohi[j] = (_Float16)(bv * c + av * sn);
  }
  *(half8*)(t + base) = olo;
  *(half8*)(t + base + 1024) = ohi;
}

// ---------- merged QKV GEMM: [2048][4096] @ [6144][4096]^T, BK=64, swizzled LDS ----------
__global__ __launch_bounds__(256, 3) void gemm_qkv(
    const _Float16* __restrict__ A, const _Float16* __restrict__ BtQ,
    const _Float16* __restrict__ BtKV, _Float16* __restrict__ Qt,
    _Float16* __restrict__ Kt, _Float16* __restrict__ Vt) {
  __shared__ _Float16 As[128 * 64];
  __shared__ _Float16 Bs[128 * 64];
  const int K = 4096;
  const int tid = threadIdx.x, lane = tid & 63, wid = tid >> 6;
  const int row0 = blockIdx.y * 128;
  const int col0 = blockIdx.x * 128;
  const int wm = wid >> 1, wn = wid & 1;
  const int lr = lane & 15, lg = lane >> 4;

  const _Float16* bbase = (col0 < 4096) ? (BtQ + (long)col0 * K)
                                        : (BtKV + (long)(col0 - 4096) * K);
  const int scol = ((lane & 7) ^ ((lane >> 3) & 7)) * 8;
  const _Float16* aptr = A + (long)(row0 + wid * 32 + (lane >> 3)) * K + scol;
  const _Float16* bptr = bbase + (long)(wid * 32 + (lane >> 3)) * K + scol;
  _Float16* alds = As + (wid * 4) * 512;
  _Float16* blds = Bs + (wid * 4) * 512;

  f32x4 acc[4][4] = {};
  for (int k0 = 0; k0 < K; k0 += 64) {
#pragma unroll
    for (int j = 0; j < 4; j++) {
      async16(alds + j * 512, aptr + k0 + (long)j * 8 * K);
      async16(blds + j * 512, bptr + k0 + (long)j * 8 * K);
    }
    __syncthreads();
    half8 a[2][4], b[2][4];
#pragma unroll
    for (int kk = 0; kk < 2; kk++)
#pragma unroll
      for (int mf = 0; mf < 4; mf++) {
        a[kk][mf] = *(const half8*)&As[(wm * 64 + mf * 16 + lr) * 64 +
                                       (((kk * 4 + lg) ^ (lr & 7)) * 8)];
        b[kk][mf] = *(const half8*)&Bs[(wn * 64 + mf * 16 + lr) * 64 +
                                       (((kk * 4 + lg) ^ (lr & 7)) * 8)];
      }
#pragma unroll
    for (int kk = 0; kk < 2; kk++)
#pragma unroll
      for (int mf = 0; mf < 4; mf++)
#pragma unroll
        for (int nf = 0; nf < 4; nf++)
          acc[mf][nf] =
              __builtin_amdgcn_mfma_f32_16x16x32_f16(a[kk][mf], b[kk][nf], acc[mf][nf], 0, 0, 0);
    __syncthreads();
  }

#pragma unroll
  for (int mf = 0; mf < 4; mf++) {
#pragma unroll
    for (int nf = 0; nf < 4; nf++) {
      int rbase = row0 + wm * 64 + mf * 16 + lg * 4;  // s
      int col = col0 + wn * 64 + nf * 16 + lr;
      if (col0 < 4096) {  // Q frag-tiled (pre-rope)
        int h = col >> 7, d = col & 127;
        long off = ((long)((h * 128 + (rbase >> 4)) * 4 + (d >> 5))) * 512 +
                   ((d >> 3) & 3) * 128 + (rbase & 15) * 8 + (d & 7);
#pragma unroll
        for (int i = 0; i < 4; i++) Qt[off + i * 8] = (_Float16)acc[mf][nf][i];
      } else if (col0 < 5120) {  // K frag-tiled (pre-rope)
        int gc = col - 4096;
        int g = gc >> 7, d = gc & 127;
        long off = ((long)((g * 128 + (rbase >> 4)) * 4 + (d >> 5))) * 512 +
                   ((d >> 3) & 3) * 128 + (rbase & 15) * 8 + (d & 7);
#pragma unroll
        for (int i = 0; i < 4; i++) Kt[off + i * 8] = (_Float16)acc[mf][nf][i];
      } else {  // V PV-fragment layout
        int gc = col - 5120;
        int gq = gc >> 7, d = gc & 127;
        int dt = d >> 4, lrr = d & 15;
        int kvb = rbase >> 5, lgv = (rbase >> 3) & 3, j = rbase & 7;
        half4 v;
#pragma unroll
        for (int i = 0; i < 4; i++) v[i] = (_Float16)acc[mf][nf][i];
        long off = ((long)(gq * 64 + kvb) * 8 + dt) * 512 + (lgv * 16 + lrr) * 8 + j;
        *(half4*)&Vt[off] = v;
      }
    }
  }
}

// ---------- O-projection GEMM: [2048][4096] f16 @ [4096][4096]^T -> f32 out ----------
__global__ __launch_bounds__(256, 3) void gemm_out(
    const _Float16* __restrict__ A, const _Float16* __restrict__ Bt,
    float* __restrict__ C) {
  __shared__ _Float16 As[128 * 64];
  __shared__ _Float16 Bs[128 * 64];
  const int K = 4096;
  const int tid = threadIdx.x, lane = tid & 63, wid = tid >> 6;
  const int row0 = blockIdx.y * 128;
  const int col0 = blockIdx.x * 128;
  const int wm = wid >> 1, wn = wid & 1;
  const int lr = lane & 15, lg = lane >> 4;

  const int scol = ((lane & 7) ^ ((lane >> 3) & 7)) * 8;
  const _Float16* aptr = A + (long)(row0 + wid * 32 + (lane >> 3)) * K + scol;
  const _Float16* bptr = Bt + (long)(col0 + wid * 32 + (lane >> 3)) * K + scol;
  _Float16* alds = As + (wid * 4) * 512;
  _Float16* blds = Bs + (wid * 4) * 512;

  f32x4 acc[4][4] = {};
  for (int k0 = 0; k0 < K; k0 += 64) {
#pragma unroll
    for (int j = 0; j < 4; j++) {
      async16(alds + j * 512, aptr + k0 + (long)j * 8 * K);
      async16(blds + j * 512, bptr + k0 + (long)j * 8 * K);
    }
    __syncthreads();
    half8 a[2][4], b[2][4];
#pragma unroll
    for (int kk = 0; kk < 2; kk++)
#pragma unroll
      for (int mf = 0; mf < 4; mf++) {
        a[kk][mf] = *(const half8*)&As[(wm * 64 + mf * 16 + lr) * 64 +
                                       (((kk * 4 + lg) ^ (lr & 7)) * 8)];
        b[kk][mf] = *(const half8*)&Bs[(wn * 64 + mf * 16 + lr) * 64 +
                                       (((kk * 4 + lg) ^ (lr & 7)) * 8)];
      }
#pragma unroll
    for (int kk = 0; kk < 2; kk++)
#pragma unroll
      for (int mf = 0; mf < 4; mf++)
#pragma unroll
        for (int nf = 0; nf < 4; nf++)
          acc[mf][nf] =
              __builtin_amdgcn_mfma_f32_16x16x32_f16(a[kk][mf], b[kk][nf], acc[mf][nf], 0, 0, 0);
    __syncthreads();
  }
#pragma unroll
  for (int mf = 0; mf < 4; mf++)
#pragma unroll
    for (int nf = 0; nf < 4; nf++) {
      int rbase = row0 + wm * 64 + mf * 16 + lg * 4;
      int col = col0 + wn * 64 + nf * 16 + lr;
#pragma unroll
      for (int i = 0; i < 4; i++)
        C[(long)(rbase + i) * 4096 + col] = acc[mf][nf][i];
    }
}

// ---------- fused causal GQA attention, LDS-shared K/V, 32 q-rows/wave, fused Q-RoPE ----------
// Qt: frag-tiled PRE-ROPE; Kt: frag-tiled roped; Vt: PV-fragment layout.
// Block: 256 thr = 4 waves = 4 q-heads of one kv-head, same 32-row q-tile.
// Grid 512 = 2 blocks/CU; complementary qt32 remap -> per-CU tile count constant.
__global__ __launch_bounds__(256, 2) void attn_kernel(
    const _Float16* __restrict__ Qt, const _Float16* __restrict__ Kt,
    const _Float16* __restrict__ Vt, _Float16* __restrict__ O,
    const float* __restrict__ cosb, const float* __restrict__ sinb) {
  __shared__ _Float16 Klds[2][4096];
  __shared__ _Float16 Vlds[2][4096];
  __shared__ _Float16 P_lds[4][1024];
  const int tid = threadIdx.x;
  const int lane = tid & 63;
  const int wid = tid >> 6;
  const int bid = blockIdx.x;  // 512
  const int g = bid & 7;
  const int qidx = bid >> 3;   // 0..63
  const int qt32 = (qidx < 32) ? (2 * qidx) : (2 * (63 - qidx) + 1);  // balance
  const int h = g * 4 + wid;
  const int qrow0 = qt32 * 32;
  const int ntiles = qt32 + 1;
  const int lr = lane & 15;
  const int lg = lane >> 4;

  // Q fragments for two 16-row groups + fused RoPE (pair: t <-> t+2, same lane)
  half8 qf[2][4];
#pragma unroll
  for (int rg = 0; rg < 2; rg++) {
    const _Float16* qp = Qt + ((long)(h * 128 + qt32 * 2 + rg) * 4) * 512 + lane * 8;
#pragma unroll
    for (int t = 0; t < 4; t++) qf[rg][t] = *(const half8*)(qp + t * 512);
    int s = qrow0 + rg * 16 + lr;
#pragma unroll
    for (int t = 0; t < 2; t++) {
      const float* cp = cosb + s * 128 + t * 32 + lg * 8;
      const float* sp = sinb + s * 128 + t * 32 + lg * 8;
#pragma unroll
      for (int j = 0; j < 8; j++) {
        float c = cp[j], sn = sp[j];
        float lo = (float)qf[rg][t][j], hi = (float)qf[rg][t + 2][j];
        qf[rg][t][j]     = (_Float16)(lo * c - hi * sn);
        qf[rg][t + 2][j] = (_Float16)(hi * c + lo * sn);
      }
    }
  }

  const _Float16* kgb = Kt + (long)g * 128 * 2048 + lane * 8;
  const _Float16* vgb = Vt + (long)g * 64 * 4096 + lane * 8;

  {
    async16(&Klds[0][(2 * wid) * 512], kgb + (2 * wid) * 512);
    async16(&Klds[0][(2 * wid + 1) * 512], kgb + (2 * wid + 1) * 512);
    async16(&Vlds[0][(2 * wid) * 512], vgb + (2 * wid) * 512);
    async16(&Vlds[0][(2 * wid + 1) * 512], vgb + (2 * wid + 1) * 512);
  }
  __syncthreads();

  f32x4 oacc[2][8] = {};
  float mrow[2][4] = {{-1e30f, -1e30f, -1e30f, -1e30f}, {-1e30f, -1e30f, -1e30f, -1e30f}};
  float lsum[2][4] = {};

  for (int t = 0; t < ntiles; t++) {
    const int kb = t * 32;
    const int cur = t & 1;
    if (t + 1 < ntiles) {
      const _Float16* ks = kgb + (long)(t + 1) * 4096;
      const _Float16* vs = vgb + (long)(t + 1) * 4096;
      async16(&Klds[cur ^ 1][(2 * wid) * 512], ks + (2 * wid) * 512);
      async16(&Klds[cur ^ 1][(2 * wid + 1) * 512], ks + (2 * wid + 1) * 512);
      async16(&Vlds[cur ^ 1][(2 * wid) * 512], vs + (2 * wid) * 512);
      async16(&Vlds[cur ^ 1][(2 * wid + 1) * 512], vs + (2 * wid + 1) * 512);
    }

    half8 kf[8];
#pragma unroll
    for (int c = 0; c < 8; c++)
      kf[c] = *(const half8*)&Klds[cur][c * 512 + lane * 8];

    f32x4 sacc[2][2] = {};
#pragma unroll
    for (int s = 0; s < 2; s++)
#pragma unroll
      for (int rg = 0; rg < 2; rg++)
#pragma unroll
        for (int t2 = 0; t2 < 4; t2++)
          sacc[s][rg] =
              __builtin_amdgcn_mfma_f32_16x16x32_f16(qf[rg][t2], kf[s * 4 + t2], sacc[s][rg], 0, 0, 0);

    half8 vf[8];
#pragma unroll
    for (int dt = 0; dt < 8; dt++)
      vf[dt] = *(const half8*)&Vlds[cur][dt * 512 + lane * 8];

    // scale + causal mask + lane-local max (deferred-max)
    float mx[2][4];
    bool grow = false;
#pragma unroll
    for (int rg = 0; rg < 2; rg++)
#pragma unroll
      for (int i = 0; i < 4; i++) {
        int qrow = qrow0 + rg * 16 + lg * 4 + i;
        float s0 = sacc[0][rg][i] * SCALE_QK;
        float s1 = sacc[1][rg][i] * SCALE_QK;
        if (kb + lr > qrow) s0 = -1e30f;
        if (kb + 16 + lr > qrow) s1 = -1e30f;
        sacc[0][rg][i] = s0; sacc[1][rg][i] = s1;
        mx[rg][i] = fmaxf(s0, s1);
        grow |= (mx[rg][i] > mrow[rg][i] + 4.0f);
      }
    if (__any((int)grow)) {  // slow path: true row-max reduce + rescale
#pragma unroll
      for (int rg = 0; rg < 2; rg++)
#pragma unroll
        for (int i = 0; i < 4; i++) {
          float m = mx[rg][i];
          m = fmaxf(m, __shfl_xor(m, 1));
          m = fmaxf(m, __shfl_xor(m, 2));
          m = fmaxf(m, __shfl_xor(m, 4));
          m = fmaxf(m, __shfl_xor(m, 8));
          float mn = fmaxf(mrow[rg][i], m);
          float scl = __expf(mrow[rg][i] - mn);
          mrow[rg][i] = mn;
          lsum[rg][i] *= scl;
#pragma unroll
          for (int dt = 0; dt < 8; dt++) oacc[rg][dt][i] *= scl;
        }
    }
#pragma unroll
    for (int rg = 0; rg < 2; rg++) {
      float p0[4], p1[4];
#pragma unroll
      for (int i = 0; i < 4; i++) {
        p0[i] = __expf(sacc[0][rg][i] - mrow[rg][i]);
        p1[i] = __expf(sacc[1][rg][i] - mrow[rg][i]);
        lsum[rg][i] += p0[i] + p1[i];
      }
#pragma unroll
      for (int i = 0; i < 4; i++) {
        P_lds[wid][rg * 512 + (lg * 4 + i) * 32 + lr] = (_Float16)p0[i];
        P_lds[wid][rg * 512 + (lg * 4 + i) * 32 + 16 + lr] = (_Float16)p1[i];
      }
    }
    half8 pa0 = *(const half8*)&P_lds[wid][lr * 32 + lg * 8];
    half8 pa1 = *(const half8*)&P_lds[wid][512 + lr * 32 + lg * 8];

#pragma unroll
    for (int dt = 0; dt < 8; dt++) {
      oacc[0][dt] = __builtin_amdgcn_mfma_f32_16x16x32_f16(pa0, vf[dt], oacc[0][dt], 0, 0, 0);
      oacc[1][dt] = __builtin_amdgcn_mfma_f32_16x16x32_f16(pa1, vf[dt], oacc[1][dt], 0, 0, 0);
    }

    __syncthreads();  // vmcnt(0): next-tile staging done; barrier: cur consumed
  }

  // final row-sum reduce, normalize, store
#pragma unroll
  for (int rg = 0; rg < 2; rg++) {
#pragma unroll
    for (int i = 0; i < 4; i++) {
      float t2 = lsum[rg][i];
      t2 += __shfl_xor(t2, 1);
      t2 += __shfl_xor(t2, 2);
      t2 += __shfl_xor(t2, 4);
      t2 += __shfl_xor(t2, 8);
      lsum[rg][i] = t2;
    }
#pragma unroll
    for (int dt = 0; dt < 8; dt++) {
#pragma unroll
      for (int i = 0; i < 4; i++) {
        float o = oacc[rg][dt][i] / lsum[rg][i];
        O[(long)(qrow0 + rg * 16 + lg * 4 + i) * HID_DIM + h * HEAD_DIM + dt * 16 + lr] =
            (_Float16)o;
      }
    }
  }
}

extern "C" void kernel_launch(void* const* d_in, const int* in_sizes, int n_in,
                              void* d_out, int out_size, void* d_ws, size_t ws_size,
                              hipStream_t stream) {
  const float* x    = (const float*)d_in[0];
  const float* cosb = (const float*)d_in[1];
  const float* sinb = (const float*)d_in[2];
  // d_in[3] = attn_mask: pure causal, implemented in-kernel
  const float* wq = (const float*)d_in[4];
  const float* wk = (const float*)d_in[5];
  const float* wv = (const float*)d_in[6];
  const float* wo = (const float*)d_in[7];
  float* out = (float*)d_out;

  char* ws = (char*)d_ws;
  _Float16* Xh    = (_Float16*)(ws);                        // [0,16M): X f16; later Oattn
  _Float16* Oattn = Xh;
  _Float16* Qt    = (_Float16*)(ws + (size_t)(16 << 20));   // [16,32M): Q frag-tiled (pre-rope)
  _Float16* Kt    = (_Float16*)(ws + (size_t)(32 << 20));   // [32,36M): K frag-tiled
  _Float16* Vt    = (_Float16*)(ws + (size_t)(36 << 20));   // [36,40M): V PV-tiled
  _Float16* WqT   = (_Float16*)(ws + (size_t)(40 << 20));   // [40,72M): wq^T, later wo^T
  _Float16* WoT   = WqT;
  _Float16* WkvT  = (_Float16*)d_out;                       // 16MB scratch in d_out
  // peak ws usage: 72 MiB

  dim3 b256(256);
  dim3 tb(32, 8);

  // X -> f16
  conv_f32_f16<<<dim3(S_LEN * HID_DIM / 4 / 256), b256, 0, stream>>>(x, Xh, S_LEN * HID_DIM / 4);

  // weight transposes: wq^T -> ws; wk^T|wv^T -> d_out scratch
  transpose_f32_f16<<<dim3(4096 / 32, 4096 / 64), tb, 0, stream>>>(wq, WqT, 4096, 4096);
  transpose_f32_f16<<<dim3(1024 / 32, 4096 / 64), tb, 0, stream>>>(wk, WkvT, 4096, 1024);
  transpose_f32_f16<<<dim3(1024 / 32, 4096 / 64), tb, 0, stream>>>(wv, WkvT + (size_t)1024 * 4096, 4096, 1024);

  // merged QKV projection (N=6144, 768 blocks = 3/CU)
  gemm_qkv<<<dim3(6144 / 128, S_LEN / 128), b256, 0, stream>>>(Xh, WqT, WkvT, Qt, Kt, Vt);

  // RoPE in place on tiled K only (Q roped inside attn)
  rope_tiled<N_KV><<<dim3(N_KV * 16384 / 256), b256, 0, stream>>>(Kt, cosb, sinb);

  // fused causal GQA attention (+Q-RoPE) -> Oattn (reuses Xh region)
  attn_kernel<<<dim3(512), b256, 0, stream>>>(Qt, Kt, Vt, Oattn, cosb, sinb);

  // out = Oattn @ Wo (f32)
  transpose_f32_f16<<<dim3(4096 / 32, 4096 / 64), tb, 0, stream>>>(wo, WoT, 4096, 4096);
  gemm_out<<<dim3(4096 / 128, S_LEN / 128), b256, 0, stream>>>(Oattn, WoT, out);
}

// Round 7
// 320.085 us; speedup vs baseline: 1.0560x; 1.0560x over previous
//
#include <hip/hip_runtime.h>
#include <hip/hip_bf16.h>
#include <hip/hip_fp16.h>

typedef _Float16 half8 __attribute__((ext_vector_type(8)));
typedef _Float16 half4 __attribute__((ext_vector_type(4)));
typedef float f32x4 __attribute__((ext_vector_type(4)));
typedef unsigned int u32;

#define S_LEN 2048
#define HID_DIM 4096
#define N_HEADS 32
#define N_KV 8
#define HEAD_DIM 128
#define SCALE_QK 0.08838834764831845f

// ---------- async global->LDS (16B per lane, wave-uniform LDS base) ----------
__device__ __forceinline__ void async16(void* lds, const void* gptr) {
  __builtin_amdgcn_global_load_lds(
      (const __attribute__((address_space(1))) u32*)gptr,
      (__attribute__((address_space(3))) u32*)lds, 16, 0, 0);
}

// ---------- f32 -> f16 convert (16B/lane both sides) ----------
__global__ void conv_f32_f16(const float* __restrict__ src, _Float16* __restrict__ dst, int n8) {
  int i = blockIdx.x * 256 + threadIdx.x;
  if (i < n8) {
    float4 a = ((const float4*)src)[2 * i];
    float4 b = ((const float4*)src)[2 * i + 1];
    half8 h;
    h[0] = (_Float16)a.x; h[1] = (_Float16)a.y; h[2] = (_Float16)a.z; h[3] = (_Float16)a.w;
    h[4] = (_Float16)b.x; h[5] = (_Float16)b.y; h[6] = (_Float16)b.z; h[7] = (_Float16)b.w;
    ((half8*)dst)[i] = h;
  }
}

// ---------- transpose f32 [R][C] -> f16 [C][R], 64x64 tiles, vectorized both sides ----------
__global__ void transpose_f32_f16(const float* __restrict__ src, _Float16* __restrict__ dst,
                                  int R, int C) {
  __shared__ float tile[64][73];  // pad 73: phase-2 banks (8*kc + 9j + n) -> 2-way max
  const int t = threadIdx.x;      // 256
  const int bx = blockIdx.x;      // over C/64
  const int by = blockIdx.y;      // over R/64
  // phase 1: float4 reads, 256B segments per 16-lane row group
  {
    const int c4 = (t & 15) * 4;
    const int r0 = t >> 4;  // 0..15
#pragma unroll
    for (int i = 0; i < 4; i++) {
      int r = r0 + 16 * i;
      float4 v = *(const float4*)&src[(long)(by * 64 + r) * C + bx * 64 + c4];
      tile[r][c4] = v.x; tile[r][c4 + 1] = v.y; tile[r][c4 + 2] = v.z; tile[r][c4 + 3] = v.w;
    }
  }
  __syncthreads();
  // phase 2: half8 writes along k (16B/lane, 128B per 8-lane group)
  const int kc = t & 7;
  const int n0 = t >> 3;  // 0..31
#pragma unroll
  for (int p = 0; p < 2; p++) {
    int n = n0 + 32 * p;
    half8 o;
#pragma unroll
    for (int j = 0; j < 8; j++) o[j] = (_Float16)tile[kc * 8 + j][n];
    *(half8*)&dst[(long)(bx * 64 + n) * R + by * 64 + kc * 8] = o;
  }
}

// ---------- RoPE in place on frag-tiled [h][s16][d/32][slot] layout (K only) ----------
template <int NHEADS>
__global__ void rope_tiled(_Float16* __restrict__ t, const float* __restrict__ cosb,
                           const float* __restrict__ sinb) {
  int idx = blockIdx.x * 256 + threadIdx.x;  // NHEADS * 2048 * 8
  int slo = idx & 15;
  int d8 = (idx >> 4) & 7;
  int h = (idx >> 7) % NHEADS;
  int s16 = idx / (128 * NHEADS);
  int s = s16 * 16 + slo;
  int d0 = d8 * 8;
  long c0 = (long)(h * 128 + s16) * 4;
  long base = (c0 + (d0 >> 5)) * 512 + ((d0 >> 3) & 3) * 128 + slo * 8;
  half8 a = *(half8*)(t + base);
  half8 b = *(half8*)(t + base + 1024);  // d0+64 -> chunk+2
  const float* cp = cosb + s * 128 + d0;
  const float* sp = sinb + s * 128 + d0;
  half8 olo, ohi;
#pragma unroll
  for (int j = 0; j < 8; j++) {
    float c = cp[j], sn = sp[j];
    float av = (float)a[j], bv = (float)b[j];
    olo[j] = (_Float16)(av * c - bv * sn);
    ohi[j] = (_Float16)(bv * c + av * sn);
  }
  *(half8*)(t + base) = olo;
  *(half8*)(t + base + 1024) = ohi;
}

// ---------- merged QKV GEMM: [2048][4096] @ [6144][4096]^T, BK=64, swizzled LDS ----------
__global__ __launch_bounds__(256, 3) void gemm_qkv(
    const _Float16* __restrict__ A, const _Float16* __restrict__ BtQ,
    const _Float16* __restrict__ BtKV, _Float16* __restrict__ Qt,
    _Float16* __restrict__ Kt, _Float16* __restrict__ Vt) {
  __shared__ _Float16 As[128 * 64];
  __shared__ _Float16 Bs[128 * 64];
  const int K = 4096;
  const int tid = threadIdx.x, lane = tid & 63, wid = tid >> 6;
  const int row0 = blockIdx.y * 128;
  const int col0 = blockIdx.x * 128;
  const int wm = wid >> 1, wn = wid & 1;
  const int lr = lane & 15, lg = lane >> 4;

  const _Float16* bbase = (col0 < 4096) ? (BtQ + (long)col0 * K)
                                        : (BtKV + (long)(col0 - 4096) * K);
  const int scol = ((lane & 7) ^ ((lane >> 3) & 7)) * 8;
  const _Float16* aptr = A + (long)(row0 + wid * 32 + (lane >> 3)) * K + scol;
  const _Float16* bptr = bbase + (long)(wid * 32 + (lane >> 3)) * K + scol;
  _Float16* alds = As + (wid * 4) * 512;
  _Float16* blds = Bs + (wid * 4) * 512;

  f32x4 acc[4][4] = {};
  for (int k0 = 0; k0 < K; k0 += 64) {
#pragma unroll
    for (int j = 0; j < 4; j++) {
      async16(alds + j * 512, aptr + k0 + (long)j * 8 * K);
      async16(blds + j * 512, bptr + k0 + (long)j * 8 * K);
    }
    __syncthreads();
    half8 a[2][4], b[2][4];
#pragma unroll
    for (int kk = 0; kk < 2; kk++)
#pragma unroll
      for (int mf = 0; mf < 4; mf++) {
        a[kk][mf] = *(const half8*)&As[(wm * 64 + mf * 16 + lr) * 64 +
                                       (((kk * 4 + lg) ^ (lr & 7)) * 8)];
        b[kk][mf] = *(const half8*)&Bs[(wn * 64 + mf * 16 + lr) * 64 +
                                       (((kk * 4 + lg) ^ (lr & 7)) * 8)];
      }
#pragma unroll
    for (int kk = 0; kk < 2; kk++)
#pragma unroll
      for (int mf = 0; mf < 4; mf++)
#pragma unroll
        for (int nf = 0; nf < 4; nf++)
          acc[mf][nf] =
              __builtin_amdgcn_mfma_f32_16x16x32_f16(a[kk][mf], b[kk][nf], acc[mf][nf], 0, 0, 0);
    __syncthreads();
  }

#pragma unroll
  for (int mf = 0; mf < 4; mf++) {
#pragma unroll
    for (int nf = 0; nf < 4; nf++) {
      int rbase = row0 + wm * 64 + mf * 16 + lg * 4;  // s
      int col = col0 + wn * 64 + nf * 16 + lr;
      if (col0 < 4096) {  // Q frag-tiled (pre-rope)
        int h = col >> 7, d = col & 127;
        long off = ((long)((h * 128 + (rbase >> 4)) * 4 + (d >> 5))) * 512 +
                   ((d >> 3) & 3) * 128 + (rbase & 15) * 8 + (d & 7);
#pragma unroll
        for (int i = 0; i < 4; i++) Qt[off + i * 8] = (_Float16)acc[mf][nf][i];
      } else if (col0 < 5120) {  // K frag-tiled (pre-rope)
        int gc = col - 4096;
        int g = gc >> 7, d = gc & 127;
        long off = ((long)((g * 128 + (rbase >> 4)) * 4 + (d >> 5))) * 512 +
                   ((d >> 3) & 3) * 128 + (rbase & 15) * 8 + (d & 7);
#pragma unroll
        for (int i = 0; i < 4; i++) Kt[off + i * 8] = (_Float16)acc[mf][nf][i];
      } else {  // V PV-fragment layout
        int gc = col - 5120;
        int gq = gc >> 7, d = gc & 127;
        int dt = d >> 4, lrr = d & 15;
        int kvb = rbase >> 5, lgv = (rbase >> 3) & 3, j = rbase & 7;
        half4 v;
#pragma unroll
        for (int i = 0; i < 4; i++) v[i] = (_Float16)acc[mf][nf][i];
        long off = ((long)(gq * 64 + kvb) * 8 + dt) * 512 + (lgv * 16 + lrr) * 8 + j;
        *(half4*)&Vt[off] = v;
      }
    }
  }
}

// ---------- O-projection GEMM: [2048][4096] f16 @ [4096][4096]^T -> f32 out ----------
__global__ __launch_bounds__(256, 3) void gemm_out(
    const _Float16* __restrict__ A, const _Float16* __restrict__ Bt,
    float* __restrict__ C) {
  __shared__ _Float16 As[128 * 64];
  __shared__ _Float16 Bs[128 * 64];
  const int K = 4096;
  const int tid = threadIdx.x, lane = tid & 63, wid = tid >> 6;
  const int row0 = blockIdx.y * 128;
  const int col0 = blockIdx.x * 128;
  const int wm = wid >> 1, wn = wid & 1;
  const int lr = lane & 15, lg = lane >> 4;

  const int scol = ((lane & 7) ^ ((lane >> 3) & 7)) * 8;
  const _Float16* aptr = A + (long)(row0 + wid * 32 + (lane >> 3)) * K + scol;
  const _Float16* bptr = Bt + (long)(col0 + wid * 32 + (lane >> 3)) * K + scol;
  _Float16* alds = As + (wid * 4) * 512;
  _Float16* blds = Bs + (wid * 4) * 512;

  f32x4 acc[4][4] = {};
  for (int k0 = 0; k0 < K; k0 += 64) {
#pragma unroll
    for (int j = 0; j < 4; j++) {
      async16(alds + j * 512, aptr + k0 + (long)j * 8 * K);
      async16(blds + j * 512, bptr + k0 + (long)j * 8 * K);
    }
    __syncthreads();
    half8 a[2][4], b[2][4];
#pragma unroll
    for (int kk = 0; kk < 2; kk++)
#pragma unroll
      for (int mf = 0; mf < 4; mf++) {
        a[kk][mf] = *(const half8*)&As[(wm * 64 + mf * 16 + lr) * 64 +
                                       (((kk * 4 + lg) ^ (lr & 7)) * 8)];
        b[kk][mf] = *(const half8*)&Bs[(wn * 64 + mf * 16 + lr) * 64 +
                                       (((kk * 4 + lg) ^ (lr & 7)) * 8)];
      }
#pragma unroll
    for (int kk = 0; kk < 2; kk++)
#pragma unroll
      for (int mf = 0; mf < 4; mf++)
#pragma unroll
        for (int nf = 0; nf < 4; nf++)
          acc[mf][nf] =
              __builtin_amdgcn_mfma_f32_16x16x32_f16(a[kk][mf], b[kk][nf], acc[mf][nf], 0, 0, 0);
    __syncthreads();
  }
#pragma unroll
  for (int mf = 0; mf < 4; mf++)
#pragma unroll
    for (int nf = 0; nf < 4; nf++) {
      int rbase = row0 + wm * 64 + mf * 16 + lg * 4;
      int col = col0 + wn * 64 + nf * 16 + lr;
#pragma unroll
      for (int i = 0; i < 4; i++)
        C[(long)(rbase + i) * 4096 + col] = acc[mf][nf][i];
    }
}

// ---------- fused causal GQA attention, LDS-shared K/V, 16 q-rows/wave, fused Q-RoPE ----------
// Block: 256 thr = 4 waves = 4 q-heads of one kv-head, same 16-row q-tile.
// Grid 1024 = 3+ blocks/CU (latency hiding across blocks); complementary qt16 remap.
__global__ __launch_bounds__(256, 3) void attn_kernel(
    const _Float16* __restrict__ Qt, const _Float16* __restrict__ Kt,
    const _Float16* __restrict__ Vt, _Float16* __restrict__ O,
    const float* __restrict__ cosb, const float* __restrict__ sinb) {
  __shared__ _Float16 Klds[2][4096];
  __shared__ _Float16 Vlds[2][4096];
  __shared__ _Float16 P_lds[4][512];
  const int tid = threadIdx.x;
  const int lane = tid & 63;
  const int wid = tid >> 6;
  const int bid = blockIdx.x;  // 1024
  const int g = bid & 7;
  const int qidx = bid >> 3;
  const int qt16 = (qidx < 64) ? (2 * qidx) : (2 * (127 - qidx) + 1);
  const int h = g * 4 + wid;
  const int qrow0 = qt16 * 16;
  const int ntiles = (qrow0 + 47) >> 5;
  const int lr = lane & 15;
  const int lg = lane >> 4;

  // Q fragments + fused RoPE (rotate-half partner: fragment t <-> t+2, same lane)
  half8 qf[4];
  {
    const _Float16* qp = Qt + ((long)(h * 128 + qt16) * 4) * 512 + lane * 8;
#pragma unroll
    for (int t = 0; t < 4; t++) qf[t] = *(const half8*)(qp + t * 512);
    int s = qrow0 + lr;
#pragma unroll
    for (int t = 0; t < 2; t++) {
      const float* cp = cosb + s * 128 + t * 32 + lg * 8;
      const float* sp = sinb + s * 128 + t * 32 + lg * 8;
#pragma unroll
      for (int j = 0; j < 8; j++) {
        float c = cp[j], sn = sp[j];
        float lo = (float)qf[t][j], hi = (float)qf[t + 2][j];
        qf[t][j]     = (_Float16)(lo * c - hi * sn);
        qf[t + 2][j] = (_Float16)(hi * c + lo * sn);
      }
    }
  }

  const _Float16* kgb = Kt + (long)g * 128 * 2048 + lane * 8;
  const _Float16* vgb = Vt + (long)g * 64 * 4096 + lane * 8;

  {
    async16(&Klds[0][(2 * wid) * 512], kgb + (2 * wid) * 512);
    async16(&Klds[0][(2 * wid + 1) * 512], kgb + (2 * wid + 1) * 512);
    async16(&Vlds[0][(2 * wid) * 512], vgb + (2 * wid) * 512);
    async16(&Vlds[0][(2 * wid + 1) * 512], vgb + (2 * wid + 1) * 512);
  }
  __syncthreads();

  f32x4 oacc[8] = {};
  float mrow[4] = {-1e30f, -1e30f, -1e30f, -1e30f};
  float lsum[4] = {0.f, 0.f, 0.f, 0.f};

  for (int t = 0; t < ntiles; t++) {
    const int kb = t * 32;
    const int cur = t & 1;
    if (t + 1 < ntiles) {
      const _Float16* ks = kgb + (long)(t + 1) * 4096;
      const _Float16* vs = vgb + (long)(t + 1) * 4096;
      async16(&Klds[cur ^ 1][(2 * wid) * 512], ks + (2 * wid) * 512);
      async16(&Klds[cur ^ 1][(2 * wid + 1) * 512], ks + (2 * wid + 1) * 512);
      async16(&Vlds[cur ^ 1][(2 * wid) * 512], vs + (2 * wid) * 512);
      async16(&Vlds[cur ^ 1][(2 * wid + 1) * 512], vs + (2 * wid + 1) * 512);
    }

    half8 kf[8];
#pragma unroll
    for (int c = 0; c < 8; c++)
      kf[c] = *(const half8*)&Klds[cur][c * 512 + lane * 8];
    half8 vf[8];
#pragma unroll
    for (int dt = 0; dt < 8; dt++)
      vf[dt] = *(const half8*)&Vlds[cur][dt * 512 + lane * 8];

    f32x4 sacc[2] = {};
#pragma unroll
    for (int s = 0; s < 2; s++)
#pragma unroll
      for (int t2 = 0; t2 < 4; t2++)
        sacc[s] = __builtin_amdgcn_mfma_f32_16x16x32_f16(qf[t2], kf[s * 4 + t2], sacc[s], 0, 0, 0);

    float mx[4];
    bool grow = false;
#pragma unroll
    for (int i = 0; i < 4; i++) {
      int qrow = qrow0 + lg * 4 + i;
      float s0 = sacc[0][i] * SCALE_QK;
      float s1 = sacc[1][i] * SCALE_QK;
      if (kb + lr > qrow) s0 = -1e30f;
      if (kb + 16 + lr > qrow) s1 = -1e30f;
      sacc[0][i] = s0; sacc[1][i] = s1;
      mx[i] = fmaxf(s0, s1);
      grow |= (mx[i] > mrow[i] + 4.0f);
    }
    if (__any((int)grow)) {
#pragma unroll
      for (int i = 0; i < 4; i++) {
        float m = mx[i];
        m = fmaxf(m, __shfl_xor(m, 1));
        m = fmaxf(m, __shfl_xor(m, 2));
        m = fmaxf(m, __shfl_xor(m, 4));
        m = fmaxf(m, __shfl_xor(m, 8));
        float mn = fmaxf(mrow[i], m);
        float scl = __expf(mrow[i] - mn);
        mrow[i] = mn;
        lsum[i] *= scl;
#pragma unroll
        for (int dt = 0; dt < 8; dt++) oacc[dt][i] *= scl;
      }
    }
    float p[2][4];
#pragma unroll
    for (int i = 0; i < 4; i++) {
      p[0][i] = __expf(sacc[0][i] - mrow[i]);
      p[1][i] = __expf(sacc[1][i] - mrow[i]);
      lsum[i] += p[0][i] + p[1][i];
    }

#pragma unroll
    for (int sub = 0; sub < 2; sub++)
#pragma unroll
      for (int i = 0; i < 4; i++)
        P_lds[wid][(lg * 4 + i) * 32 + sub * 16 + lr] = (_Float16)p[sub][i];
    half8 pa = *(const half8*)&P_lds[wid][lr * 32 + lg * 8];

#pragma unroll
    for (int dt = 0; dt < 8; dt++)
      oacc[dt] = __builtin_amdgcn_mfma_f32_16x16x32_f16(pa, vf[dt], oacc[dt], 0, 0, 0);

    __syncthreads();
  }

#pragma unroll
  for (int i = 0; i < 4; i++) {
    float t2 = lsum[i];
    t2 += __shfl_xor(t2, 1);
    t2 += __shfl_xor(t2, 2);
    t2 += __shfl_xor(t2, 4);
    t2 += __shfl_xor(t2, 8);
    lsum[i] = t2;
  }
#pragma unroll
  for (int dt = 0; dt < 8; dt++) {
#pragma unroll
    for (int i = 0; i < 4; i++) {
      float o = oacc[dt][i] / lsum[i];
      O[(long)(qrow0 + lg * 4 + i) * HID_DIM + h * HEAD_DIM + dt * 16 + lr] = (_Float16)o;
    }
  }
}

extern "C" void kernel_launch(void* const* d_in, const int* in_sizes, int n_in,
                              void* d_out, int out_size, void* d_ws, size_t ws_size,
                              hipStream_t stream) {
  const float* x    = (const float*)d_in[0];
  const float* cosb = (const float*)d_in[1];
  const float* sinb = (const float*)d_in[2];
  // d_in[3] = attn_mask: pure causal, implemented in-kernel
  const float* wq = (const float*)d_in[4];
  const float* wk = (const float*)d_in[5];
  const float* wv = (const float*)d_in[6];
  const float* wo = (const float*)d_in[7];
  float* out = (float*)d_out;

  char* ws = (char*)d_ws;
  _Float16* Xh    = (_Float16*)(ws);                        // [0,16M): X f16; later Oattn
  _Float16* Oattn = Xh;
  _Float16* Qt    = (_Float16*)(ws + (size_t)(16 << 20));   // [16,32M): Q frag-tiled (pre-rope)
  _Float16* Kt    = (_Float16*)(ws + (size_t)(32 << 20));   // [32,36M): K frag-tiled
  _Float16* Vt    = (_Float16*)(ws + (size_t)(36 << 20));   // [36,40M): V PV-tiled
  _Float16* WqT   = (_Float16*)(ws + (size_t)(40 << 20));   // [40,72M): wq^T, later wo^T
  _Float16* WoT   = WqT;
  _Float16* WkvT  = (_Float16*)d_out;                       // 16MB scratch in d_out
  // peak ws usage: 72 MiB

  dim3 b256(256);

  // X -> f16
  conv_f32_f16<<<dim3(S_LEN * HID_DIM / 8 / 256), b256, 0, stream>>>(x, Xh, S_LEN * HID_DIM / 8);

  // weight transposes (vectorized): wq^T -> ws; wk^T|wv^T -> d_out scratch
  transpose_f32_f16<<<dim3(4096 / 64, 4096 / 64), b256, 0, stream>>>(wq, WqT, 4096, 4096);
  transpose_f32_f16<<<dim3(1024 / 64, 4096 / 64), b256, 0, stream>>>(wk, WkvT, 4096, 1024);
  transpose_f32_f16<<<dim3(1024 / 64, 4096 / 64), b256, 0, stream>>>(wv, WkvT + (size_t)1024 * 4096, 4096, 1024);

  // merged QKV projection (N=6144, 768 blocks = 3/CU)
  gemm_qkv<<<dim3(6144 / 128, S_LEN / 128), b256, 0, stream>>>(Xh, WqT, WkvT, Qt, Kt, Vt);

  // RoPE in place on tiled K only (Q roped inside attn)
  rope_tiled<N_KV><<<dim3(N_KV * 16384 / 256), b256, 0, stream>>>(Kt, cosb, sinb);

  // fused causal GQA attention (+Q-RoPE) -> Oattn (reuses Xh region)
  attn_kernel<<<dim3(1024), b256, 0, stream>>>(Qt, Kt, Vt, Oattn, cosb, sinb);

  // out = Oattn @ Wo (f32)
  transpose_f32_f16<<<dim3(4096 / 64, 4096 / 64), b256, 0, stream>>>(wo, WoT, 4096, 4096);
  gemm_out<<<dim3(4096 / 128, S_LEN / 128), b256, 0, stream>>>(Oattn, WoT, out);
}

// Round 8
// 317.112 us; speedup vs baseline: 1.0659x; 1.0094x over previous
//
#include <hip/hip_runtime.h>
#include <hip/hip_bf16.h>
#include <hip/hip_fp16.h>

typedef _Float16 half8 __attribute__((ext_vector_type(8)));
typedef _Float16 half4 __attribute__((ext_vector_type(4)));
typedef float f32x4 __attribute__((ext_vector_type(4)));
typedef unsigned int u32;

#define S_LEN 2048
#define HID_DIM 4096
#define N_HEADS 32
#define N_KV 8
#define HEAD_DIM 128
#define SCALE_QK 0.08838834764831845f

// ---------- async global->LDS (16B per lane, wave-uniform LDS base) ----------
__device__ __forceinline__ void async16(void* lds, const void* gptr) {
  __builtin_amdgcn_global_load_lds(
      (const __attribute__((address_space(1))) u32*)gptr,
      (__attribute__((address_space(3))) u32*)lds, 16, 0, 0);
}

// ---------- 64x64 transpose tile body (f32 [R][C] -> f16 [C][R]) ----------
__device__ __forceinline__ void transpose_tile(const float* __restrict__ src,
                                               _Float16* __restrict__ dst, int R, int C,
                                               int bx, int by, float (*tile)[73], int t) {
  // phase 1: float4 reads, 256B segments per 16-lane row group
  {
    const int c4 = (t & 15) * 4;
    const int r0 = t >> 4;  // 0..15
#pragma unroll
    for (int i = 0; i < 4; i++) {
      int r = r0 + 16 * i;
      float4 v = *(const float4*)&src[(long)(by * 64 + r) * C + bx * 64 + c4];
      tile[r][c4] = v.x; tile[r][c4 + 1] = v.y; tile[r][c4 + 2] = v.z; tile[r][c4 + 3] = v.w;
    }
  }
  __syncthreads();
  // phase 2: half8 writes along k (16B/lane, 128B per 8-lane group)
  const int kc = t & 7;
  const int n0 = t >> 3;  // 0..31
#pragma unroll
  for (int p = 0; p < 2; p++) {
    int n = n0 + 32 * p;
    half8 o;
#pragma unroll
    for (int j = 0; j < 8; j++) o[j] = (_Float16)tile[kc * 8 + j][n];
    *(half8*)&dst[(long)(bx * 64 + n) * R + by * 64 + kc * 8] = o;
  }
}

// ---------- merged prep: X conversion + wq^T + wk^T + wv^T in ONE dispatch ----------
// blocks [0,4096): conv X; [4096,8192): wq^T; [8192,9216): wk^T; [9216,10240): wv^T
__global__ void prep_kernel(const float* __restrict__ x, _Float16* __restrict__ Xh,
                            const float* __restrict__ wq, _Float16* __restrict__ WqT,
                            const float* __restrict__ wk, const float* __restrict__ wv,
                            _Float16* __restrict__ WkvT) {
  __shared__ float tile[64][73];  // pad 73: phase-2 banks 2-way max
  const int bid = blockIdx.x;
  const int t = threadIdx.x;
  if (bid < 4096) {  // conv: 4096*256 == S*HID/8 exactly
    int i = bid * 256 + t;
    float4 a = ((const float4*)x)[2 * i];
    float4 b = ((const float4*)x)[2 * i + 1];
    half8 h;
    h[0] = (_Float16)a.x; h[1] = (_Float16)a.y; h[2] = (_Float16)a.z; h[3] = (_Float16)a.w;
    h[4] = (_Float16)b.x; h[5] = (_Float16)b.y; h[6] = (_Float16)b.z; h[7] = (_Float16)b.w;
    ((half8*)Xh)[i] = h;
  } else if (bid < 8192) {  // wq^T: [4096][4096], 64x64 grid
    int tt = bid - 4096;
    transpose_tile(wq, WqT, 4096, 4096, tt & 63, tt >> 6, tile, t);
  } else if (bid < 9216) {  // wk^T: [4096][1024], 16x64 grid
    int tt = bid - 8192;
    transpose_tile(wk, WkvT, 4096, 1024, tt & 15, tt >> 4, tile, t);
  } else {  // wv^T
    int tt = bid - 9216;
    transpose_tile(wv, WkvT + (size_t)1024 * 4096, 4096, 1024, tt & 15, tt >> 4, tile, t);
  }
}

// ---------- standalone transpose (wo^T, must run after attn frees the buffer) ----------
__global__ void transpose_f32_f16(const float* __restrict__ src, _Float16* __restrict__ dst,
                                  int R, int C) {
  __shared__ float tile[64][73];
  transpose_tile(src, dst, R, C, blockIdx.x, blockIdx.y, tile, threadIdx.x);
}

// ---------- RoPE in place on frag-tiled [h][s16][d/32][slot] layout (K only) ----------
template <int NHEADS>
__global__ void rope_tiled(_Float16* __restrict__ t, const float* __restrict__ cosb,
                           const float* __restrict__ sinb) {
  int idx = blockIdx.x * 256 + threadIdx.x;  // NHEADS * 2048 * 8
  int slo = idx & 15;
  int d8 = (idx >> 4) & 7;
  int h = (idx >> 7) % NHEADS;
  int s16 = idx / (128 * NHEADS);
  int s = s16 * 16 + slo;
  int d0 = d8 * 8;
  long c0 = (long)(h * 128 + s16) * 4;
  long base = (c0 + (d0 >> 5)) * 512 + ((d0 >> 3) & 3) * 128 + slo * 8;
  half8 a = *(half8*)(t + base);
  half8 b = *(half8*)(t + base + 1024);  // d0+64 -> chunk+2
  const float* cp = cosb + s * 128 + d0;
  const float* sp = sinb + s * 128 + d0;
  half8 olo, ohi;
#pragma unroll
  for (int j = 0; j < 8; j++) {
    float c = cp[j], sn = sp[j];
    float av = (float)a[j], bv = (float)b[j];
    olo[j] = (_Float16)(av * c - bv * sn);
    ohi[j] = (_Float16)(bv * c + av * sn);
  }
  *(half8*)(t + base) = olo;
  *(half8*)(t + base + 1024) = ohi;
}

// ---------- merged QKV GEMM: [2048][4096] @ [6144][4096]^T, BK=64, swizzled LDS ----------
__global__ __launch_bounds__(256, 3) void gemm_qkv(
    const _Float16* __restrict__ A, const _Float16* __restrict__ BtQ,
    const _Float16* __restrict__ BtKV, _Float16* __restrict__ Qt,
    _Float16* __restrict__ Kt, _Float16* __restrict__ Vt) {
  __shared__ _Float16 As[128 * 64];
  __shared__ _Float16 Bs[128 * 64];
  const int K = 4096;
  const int tid = threadIdx.x, lane = tid & 63, wid = tid >> 6;
  const int row0 = blockIdx.y * 128;
  const int col0 = blockIdx.x * 128;
  const int wm = wid >> 1, wn = wid & 1;
  const int lr = lane & 15, lg = lane >> 4;

  const _Float16* bbase = (col0 < 4096) ? (BtQ + (long)col0 * K)
                                        : (BtKV + (long)(col0 - 4096) * K);
  const int scol = ((lane & 7) ^ ((lane >> 3) & 7)) * 8;
  const _Float16* aptr = A + (long)(row0 + wid * 32 + (lane >> 3)) * K + scol;
  const _Float16* bptr = bbase + (long)(wid * 32 + (lane >> 3)) * K + scol;
  _Float16* alds = As + (wid * 4) * 512;
  _Float16* blds = Bs + (wid * 4) * 512;

  f32x4 acc[4][4] = {};
  for (int k0 = 0; k0 < K; k0 += 64) {
#pragma unroll
    for (int j = 0; j < 4; j++) {
      async16(alds + j * 512, aptr + k0 + (long)j * 8 * K);
      async16(blds + j * 512, bptr + k0 + (long)j * 8 * K);
    }
    __syncthreads();
    half8 a[2][4], b[2][4];
#pragma unroll
    for (int kk = 0; kk < 2; kk++)
#pragma unroll
      for (int mf = 0; mf < 4; mf++) {
        a[kk][mf] = *(const half8*)&As[(wm * 64 + mf * 16 + lr) * 64 +
                                       (((kk * 4 + lg) ^ (lr & 7)) * 8)];
        b[kk][mf] = *(const half8*)&Bs[(wn * 64 + mf * 16 + lr) * 64 +
                                       (((kk * 4 + lg) ^ (lr & 7)) * 8)];
      }
#pragma unroll
    for (int kk = 0; kk < 2; kk++)
#pragma unroll
      for (int mf = 0; mf < 4; mf++)
#pragma unroll
        for (int nf = 0; nf < 4; nf++)
          acc[mf][nf] =
              __builtin_amdgcn_mfma_f32_16x16x32_f16(a[kk][mf], b[kk][nf], acc[mf][nf], 0, 0, 0);
    __syncthreads();
  }

#pragma unroll
  for (int mf = 0; mf < 4; mf++) {
#pragma unroll
    for (int nf = 0; nf < 4; nf++) {
      int rbase = row0 + wm * 64 + mf * 16 + lg * 4;  // s
      int col = col0 + wn * 64 + nf * 16 + lr;
      if (col0 < 4096) {  // Q frag-tiled (pre-rope)
        int h = col >> 7, d = col & 127;
        long off = ((long)((h * 128 + (rbase >> 4)) * 4 + (d >> 5))) * 512 +
                   ((d >> 3) & 3) * 128 + (rbase & 15) * 8 + (d & 7);
#pragma unroll
        for (int i = 0; i < 4; i++) Qt[off + i * 8] = (_Float16)acc[mf][nf][i];
      } else if (col0 < 5120) {  // K frag-tiled (pre-rope)
        int gc = col - 4096;
        int g = gc >> 7, d = gc & 127;
        long off = ((long)((g * 128 + (rbase >> 4)) * 4 + (d >> 5))) * 512 +
                   ((d >> 3) & 3) * 128 + (rbase & 15) * 8 + (d & 7);
#pragma unroll
        for (int i = 0; i < 4; i++) Kt[off + i * 8] = (_Float16)acc[mf][nf][i];
      } else {  // V PV-fragment layout
        int gc = col - 5120;
        int gq = gc >> 7, d = gc & 127;
        int dt = d >> 4, lrr = d & 15;
        int kvb = rbase >> 5, lgv = (rbase >> 3) & 3, j = rbase & 7;
        half4 v;
#pragma unroll
        for (int i = 0; i < 4; i++) v[i] = (_Float16)acc[mf][nf][i];
        long off = ((long)(gq * 64 + kvb) * 8 + dt) * 512 + (lgv * 16 + lrr) * 8 + j;
        *(half4*)&Vt[off] = v;
      }
    }
  }
}

// ---------- O-projection GEMM: [2048][4096] f16 @ [4096][4096]^T -> f32 out ----------
__global__ __launch_bounds__(256, 3) void gemm_out(
    const _Float16* __restrict__ A, const _Float16* __restrict__ Bt,
    float* __restrict__ C) {
  __shared__ _Float16 As[128 * 64];
  __shared__ _Float16 Bs[128 * 64];
  const int K = 4096;
  const int tid = threadIdx.x, lane = tid & 63, wid = tid >> 6;
  const int row0 = blockIdx.y * 128;
  const int col0 = blockIdx.x * 128;
  const int wm = wid >> 1, wn = wid & 1;
  const int lr = lane & 15, lg = lane >> 4;

  const int scol = ((lane & 7) ^ ((lane >> 3) & 7)) * 8;
  const _Float16* aptr = A + (long)(row0 + wid * 32 + (lane >> 3)) * K + scol;
  const _Float16* bptr = Bt + (long)(col0 + wid * 32 + (lane >> 3)) * K + scol;
  _Float16* alds = As + (wid * 4) * 512;
  _Float16* blds = Bs + (wid * 4) * 512;

  f32x4 acc[4][4] = {};
  for (int k0 = 0; k0 < K; k0 += 64) {
#pragma unroll
    for (int j = 0; j < 4; j++) {
      async16(alds + j * 512, aptr + k0 + (long)j * 8 * K);
      async16(blds + j * 512, bptr + k0 + (long)j * 8 * K);
    }
    __syncthreads();
    half8 a[2][4], b[2][4];
#pragma unroll
    for (int kk = 0; kk < 2; kk++)
#pragma unroll
      for (int mf = 0; mf < 4; mf++) {
        a[kk][mf] = *(const half8*)&As[(wm * 64 + mf * 16 + lr) * 64 +
                                       (((kk * 4 + lg) ^ (lr & 7)) * 8)];
        b[kk][mf] = *(const half8*)&Bs[(wn * 64 + mf * 16 + lr) * 64 +
                                       (((kk * 4 + lg) ^ (lr & 7)) * 8)];
      }
#pragma unroll
    for (int kk = 0; kk < 2; kk++)
#pragma unroll
      for (int mf = 0; mf < 4; mf++)
#pragma unroll
        for (int nf = 0; nf < 4; nf++)
          acc[mf][nf] =
              __builtin_amdgcn_mfma_f32_16x16x32_f16(a[kk][mf], b[kk][nf], acc[mf][nf], 0, 0, 0);
    __syncthreads();
  }
#pragma unroll
  for (int mf = 0; mf < 4; mf++)
#pragma unroll
    for (int nf = 0; nf < 4; nf++) {
      int rbase = row0 + wm * 64 + mf * 16 + lg * 4;
      int col = col0 + wn * 64 + nf * 16 + lr;
#pragma unroll
      for (int i = 0; i < 4; i++)
        C[(long)(rbase + i) * 4096 + col] = acc[mf][nf][i];
    }
}

// ---------- fused causal GQA attention, LDS-shared K/V, 16 q-rows/wave, fused Q-RoPE ----------
__global__ __launch_bounds__(256, 3) void attn_kernel(
    const _Float16* __restrict__ Qt, const _Float16* __restrict__ Kt,
    const _Float16* __restrict__ Vt, _Float16* __restrict__ O,
    const float* __restrict__ cosb, const float* __restrict__ sinb) {
  __shared__ _Float16 Klds[2][4096];
  __shared__ _Float16 Vlds[2][4096];
  __shared__ _Float16 P_lds[4][512];
  const int tid = threadIdx.x;
  const int lane = tid & 63;
  const int wid = tid >> 6;
  const int bid = blockIdx.x;  // 1024
  const int g = bid & 7;
  const int qidx = bid >> 3;
  const int qt16 = (qidx < 64) ? (2 * qidx) : (2 * (127 - qidx) + 1);
  const int h = g * 4 + wid;
  const int qrow0 = qt16 * 16;
  const int ntiles = (qrow0 + 47) >> 5;
  const int lr = lane & 15;
  const int lg = lane >> 4;

  // Q fragments + fused RoPE (rotate-half partner: fragment t <-> t+2, same lane)
  half8 qf[4];
  {
    const _Float16* qp = Qt + ((long)(h * 128 + qt16) * 4) * 512 + lane * 8;
#pragma unroll
    for (int t = 0; t < 4; t++) qf[t] = *(const half8*)(qp + t * 512);
    int s = qrow0 + lr;
#pragma unroll
    for (int t = 0; t < 2; t++) {
      const float* cp = cosb + s * 128 + t * 32 + lg * 8;
      const float* sp = sinb + s * 128 + t * 32 + lg * 8;
#pragma unroll
      for (int j = 0; j < 8; j++) {
        float c = cp[j], sn = sp[j];
        float lo = (float)qf[t][j], hi = (float)qf[t + 2][j];
        qf[t][j]     = (_Float16)(lo * c - hi * sn);
        qf[t + 2][j] = (_Float16)(hi * c + lo * sn);
      }
    }
  }

  const _Float16* kgb = Kt + (long)g * 128 * 2048 + lane * 8;
  const _Float16* vgb = Vt + (long)g * 64 * 4096 + lane * 8;

  {
    async16(&Klds[0][(2 * wid) * 512], kgb + (2 * wid) * 512);
    async16(&Klds[0][(2 * wid + 1) * 512], kgb + (2 * wid + 1) * 512);
    async16(&Vlds[0][(2 * wid) * 512], vgb + (2 * wid) * 512);
    async16(&Vlds[0][(2 * wid + 1) * 512], vgb + (2 * wid + 1) * 512);
  }
  __syncthreads();

  f32x4 oacc[8] = {};
  float mrow[4] = {-1e30f, -1e30f, -1e30f, -1e30f};
  float lsum[4] = {0.f, 0.f, 0.f, 0.f};

  for (int t = 0; t < ntiles; t++) {
    const int kb = t * 32;
    const int cur = t & 1;
    if (t + 1 < ntiles) {
      const _Float16* ks = kgb + (long)(t + 1) * 4096;
      const _Float16* vs = vgb + (long)(t + 1) * 4096;
      async16(&Klds[cur ^ 1][(2 * wid) * 512], ks + (2 * wid) * 512);
      async16(&Klds[cur ^ 1][(2 * wid + 1) * 512], ks + (2 * wid + 1) * 512);
      async16(&Vlds[cur ^ 1][(2 * wid) * 512], vs + (2 * wid) * 512);
      async16(&Vlds[cur ^ 1][(2 * wid + 1) * 512], vs + (2 * wid + 1) * 512);
    }

    half8 kf[8];
#pragma unroll
    for (int c = 0; c < 8; c++)
      kf[c] = *(const half8*)&Klds[cur][c * 512 + lane * 8];
    half8 vf[8];
#pragma unroll
    for (int dt = 0; dt < 8; dt++)
      vf[dt] = *(const half8*)&Vlds[cur][dt * 512 + lane * 8];

    f32x4 sacc[2] = {};
    __builtin_amdgcn_s_setprio(1);
#pragma unroll
    for (int s = 0; s < 2; s++)
#pragma unroll
      for (int t2 = 0; t2 < 4; t2++)
        sacc[s] = __builtin_amdgcn_mfma_f32_16x16x32_f16(qf[t2], kf[s * 4 + t2], sacc[s], 0, 0, 0);
    __builtin_amdgcn_s_setprio(0);

    float mx[4];
    bool grow = false;
#pragma unroll
    for (int i = 0; i < 4; i++) {
      int qrow = qrow0 + lg * 4 + i;
      float s0 = sacc[0][i] * SCALE_QK;
      float s1 = sacc[1][i] * SCALE_QK;
      if (kb + lr > qrow) s0 = -1e30f;
      if (kb + 16 + lr > qrow) s1 = -1e30f;
      sacc[0][i] = s0; sacc[1][i] = s1;
      mx[i] = fmaxf(s0, s1);
      grow |= (mx[i] > mrow[i] + 4.0f);
    }
    if (__any((int)grow)) {
#pragma unroll
      for (int i = 0; i < 4; i++) {
        float m = mx[i];
        m = fmaxf(m, __shfl_xor(m, 1));
        m = fmaxf(m, __shfl_xor(m, 2));
        m = fmaxf(m, __shfl_xor(m, 4));
        m = fmaxf(m, __shfl_xor(m, 8));
        float mn = fmaxf(mrow[i], m);
        float scl = __expf(mrow[i] - mn);
        mrow[i] = mn;
        lsum[i] *= scl;
#pragma unroll
        for (int dt = 0; dt < 8; dt++) oacc[dt][i] *= scl;
      }
    }
    float p[2][4];
#pragma unroll
    for (int i = 0; i < 4; i++) {
      p[0][i] = __expf(sacc[0][i] - mrow[i]);
      p[1][i] = __expf(sacc[1][i] - mrow[i]);
      lsum[i] += p[0][i] + p[1][i];
    }

#pragma unroll
    for (int sub = 0; sub < 2; sub++)
#pragma unroll
      for (int i = 0; i < 4; i++)
        P_lds[wid][(lg * 4 + i) * 32 + sub * 16 + lr] = (_Float16)p[sub][i];
    half8 pa = *(const half8*)&P_lds[wid][lr * 32 + lg * 8];

    __builtin_amdgcn_s_setprio(1);
#pragma unroll
    for (int dt = 0; dt < 8; dt++)
      oacc[dt] = __builtin_amdgcn_mfma_f32_16x16x32_f16(pa, vf[dt], oacc[dt], 0, 0, 0);
    __builtin_amdgcn_s_setprio(0);

    __syncthreads();
  }

#pragma unroll
  for (int i = 0; i < 4; i++) {
    float t2 = lsum[i];
    t2 += __shfl_xor(t2, 1);
    t2 += __shfl_xor(t2, 2);
    t2 += __shfl_xor(t2, 4);
    t2 += __shfl_xor(t2, 8);
    lsum[i] = t2;
  }
#pragma unroll
  for (int dt = 0; dt < 8; dt++) {
#pragma unroll
    for (int i = 0; i < 4; i++) {
      float o = oacc[dt][i] / lsum[i];
      O[(long)(qrow0 + lg * 4 + i) * HID_DIM + h * HEAD_DIM + dt * 16 + lr] = (_Float16)o;
    }
  }
}

extern "C" void kernel_launch(void* const* d_in, const int* in_sizes, int n_in,
                              void* d_out, int out_size, void* d_ws, size_t ws_size,
                              hipStream_t stream) {
  const float* x    = (const float*)d_in[0];
  const float* cosb = (const float*)d_in[1];
  const float* sinb = (const float*)d_in[2];
  // d_in[3] = attn_mask: pure causal, implemented in-kernel
  const float* wq = (const float*)d_in[4];
  const float* wk = (const float*)d_in[5];
  const float* wv = (const float*)d_in[6];
  const float* wo = (const float*)d_in[7];
  float* out = (float*)d_out;

  char* ws = (char*)d_ws;
  _Float16* Xh    = (_Float16*)(ws);                        // [0,16M): X f16; later Oattn
  _Float16* Oattn = Xh;
  _Float16* Qt    = (_Float16*)(ws + (size_t)(16 << 20));   // [16,32M): Q frag-tiled (pre-rope)
  _Float16* Kt    = (_Float16*)(ws + (size_t)(32 << 20));   // [32,36M): K frag-tiled
  _Float16* Vt    = (_Float16*)(ws + (size_t)(36 << 20));   // [36,40M): V PV-tiled
  _Float16* WqT   = (_Float16*)(ws + (size_t)(40 << 20));   // [40,72M): wq^T, later wo^T
  _Float16* WoT   = WqT;
  _Float16* WkvT  = (_Float16*)d_out;                       // 16MB scratch in d_out
  // peak ws usage: 72 MiB

  dim3 b256(256);

  // merged prep: X->f16 + wq^T + wk^T + wv^T (one dispatch, 10240 blocks)
  prep_kernel<<<dim3(10240), b256, 0, stream>>>(x, Xh, wq, WqT, wk, wv, WkvT);

  // merged QKV projection (N=6144, 768 blocks = 3/CU)
  gemm_qkv<<<dim3(6144 / 128, S_LEN / 128), b256, 0, stream>>>(Xh, WqT, WkvT, Qt, Kt, Vt);

  // RoPE in place on tiled K only (Q roped inside attn)
  rope_tiled<N_KV><<<dim3(N_KV * 16384 / 256), b256, 0, stream>>>(Kt, cosb, sinb);

  // fused causal GQA attention (+Q-RoPE) -> Oattn (reuses Xh region)
  attn_kernel<<<dim3(1024), b256, 0, stream>>>(Qt, Kt, Vt, Oattn, cosb, sinb);

  // out = Oattn @ Wo (f32)
  transpose_f32_f16<<<dim3(4096 / 64, 4096 / 64), b256, 0, stream>>>(wo, WoT, 4096, 4096);
  gemm_out<<<dim3(4096 / 128, S_LEN / 128), b256, 0, stream>>>(Oattn, WoT, out);
}

// Round 9
// 296.748 us; speedup vs baseline: 1.1390x; 1.0686x over previous
//
#include <hip/hip_runtime.h>
#include <hip/hip_bf16.h>
#include <hip/hip_fp16.h>

typedef _Float16 half8 __attribute__((ext_vector_type(8)));
typedef _Float16 half4 __attribute__((ext_vector_type(4)));
typedef float f32x4 __attribute__((ext_vector_type(4)));
typedef unsigned int u32;

#define S_LEN 2048
#define HID_DIM 4096
#define N_HEADS 32
#define N_KV 8
#define HEAD_DIM 128
#define SCALE_QK 0.08838834764831845f

// ---------- async global->LDS (16B per lane, wave-uniform LDS base) ----------
__device__ __forceinline__ void async16(void* lds, const void* gptr) {
  __builtin_amdgcn_global_load_lds(
      (const __attribute__((address_space(1))) u32*)gptr,
      (__attribute__((address_space(3))) u32*)lds, 16, 0, 0);
}

// ---------- 64x64 transpose tile body (f32 [R][C] -> f16 [C][R]) ----------
__device__ __forceinline__ void transpose_tile(const float* __restrict__ src,
                                               _Float16* __restrict__ dst, int R, int C,
                                               int bx, int by, float (*tile)[73], int t) {
  // phase 1: float4 reads, 256B segments per 16-lane row group
  {
    const int c4 = (t & 15) * 4;
    const int r0 = t >> 4;  // 0..15
#pragma unroll
    for (int i = 0; i < 4; i++) {
      int r = r0 + 16 * i;
      float4 v = *(const float4*)&src[(long)(by * 64 + r) * C + bx * 64 + c4];
      tile[r][c4] = v.x; tile[r][c4 + 1] = v.y; tile[r][c4 + 2] = v.z; tile[r][c4 + 3] = v.w;
    }
  }
  __syncthreads();
  // phase 2: half8 writes along k (16B/lane, 128B per 8-lane group)
  const int kc = t & 7;
  const int n0 = t >> 3;  // 0..31
#pragma unroll
  for (int p = 0; p < 2; p++) {
    int n = n0 + 32 * p;
    half8 o;
#pragma unroll
    for (int j = 0; j < 8; j++) o[j] = (_Float16)tile[kc * 8 + j][n];
    *(half8*)&dst[(long)(bx * 64 + n) * R + by * 64 + kc * 8] = o;
  }
}

// ---------- merged prep: X conversion + wq^T + wk^T + wv^T in ONE dispatch ----------
// blocks [0,4096): conv X; [4096,8192): wq^T; [8192,9216): wk^T; [9216,10240): wv^T
__global__ void prep_kernel(const float* __restrict__ x, _Float16* __restrict__ Xh,
                            const float* __restrict__ wq, _Float16* __restrict__ WqT,
                            const float* __restrict__ wk, const float* __restrict__ wv,
                            _Float16* __restrict__ WkvT) {
  __shared__ float tile[64][73];  // pad 73: phase-2 banks 2-way max
  const int bid = blockIdx.x;
  const int t = threadIdx.x;
  if (bid < 4096) {  // conv: 4096*256 == S*HID/8 exactly
    int i = bid * 256 + t;
    float4 a = ((const float4*)x)[2 * i];
    float4 b = ((const float4*)x)[2 * i + 1];
    half8 h;
    h[0] = (_Float16)a.x; h[1] = (_Float16)a.y; h[2] = (_Float16)a.z; h[3] = (_Float16)a.w;
    h[4] = (_Float16)b.x; h[5] = (_Float16)b.y; h[6] = (_Float16)b.z; h[7] = (_Float16)b.w;
    ((half8*)Xh)[i] = h;
  } else if (bid < 8192) {  // wq^T: [4096][4096], 64x64 grid
    int tt = bid - 4096;
    transpose_tile(wq, WqT, 4096, 4096, tt & 63, tt >> 6, tile, t);
  } else if (bid < 9216) {  // wk^T: [4096][1024], 16x64 grid
    int tt = bid - 8192;
    transpose_tile(wk, WkvT, 4096, 1024, tt & 15, tt >> 4, tile, t);
  } else {  // wv^T
    int tt = bid - 9216;
    transpose_tile(wv, WkvT + (size_t)1024 * 4096, 4096, 1024, tt & 15, tt >> 4, tile, t);
  }
}

// ---------- RoPE in place on frag-tiled [h][s16][d/32][slot] layout (K only) ----------
template <int NHEADS>
__global__ void rope_tiled(_Float16* __restrict__ t, const float* __restrict__ cosb,
                           const float* __restrict__ sinb) {
  int idx = blockIdx.x * 256 + threadIdx.x;  // NHEADS * 2048 * 8
  int slo = idx & 15;
  int d8 = (idx >> 4) & 7;
  int h = (idx >> 7) % NHEADS;
  int s16 = idx / (128 * NHEADS);
  int s = s16 * 16 + slo;
  int d0 = d8 * 8;
  long c0 = (long)(h * 128 + s16) * 4;
  long base = (c0 + (d0 >> 5)) * 512 + ((d0 >> 3) & 3) * 128 + slo * 8;
  half8 a = *(half8*)(t + base);
  half8 b = *(half8*)(t + base + 1024);  // d0+64 -> chunk+2
  const float* cp = cosb + s * 128 + d0;
  const float* sp = sinb + s * 128 + d0;
  half8 olo, ohi;
#pragma unroll
  for (int j = 0; j < 8; j++) {
    float c = cp[j], sn = sp[j];
    float av = (float)a[j], bv = (float)b[j];
    olo[j] = (_Float16)(av * c - bv * sn);
    ohi[j] = (_Float16)(bv * c + av * sn);
  }
  *(half8*)(t + base) = olo;
  *(half8*)(t + base + 1024) = ohi;
}

// ---------- merged QKV GEMM: [2048][4096] @ [6144][4096]^T, BK=64, swizzled LDS ----------
__global__ __launch_bounds__(256, 3) void gemm_qkv(
    const _Float16* __restrict__ A, const _Float16* __restrict__ BtQ,
    const _Float16* __restrict__ BtKV, _Float16* __restrict__ Qt,
    _Float16* __restrict__ Kt, _Float16* __restrict__ Vt) {
  __shared__ _Float16 As[128 * 64];
  __shared__ _Float16 Bs[128 * 64];
  const int K = 4096;
  const int tid = threadIdx.x, lane = tid & 63, wid = tid >> 6;
  const int row0 = blockIdx.y * 128;
  const int col0 = blockIdx.x * 128;
  const int wm = wid >> 1, wn = wid & 1;
  const int lr = lane & 15, lg = lane >> 4;

  const _Float16* bbase = (col0 < 4096) ? (BtQ + (long)col0 * K)
                                        : (BtKV + (long)(col0 - 4096) * K);
  const int scol = ((lane & 7) ^ ((lane >> 3) & 7)) * 8;
  const _Float16* aptr = A + (long)(row0 + wid * 32 + (lane >> 3)) * K + scol;
  const _Float16* bptr = bbase + (long)(wid * 32 + (lane >> 3)) * K + scol;
  _Float16* alds = As + (wid * 4) * 512;
  _Float16* blds = Bs + (wid * 4) * 512;

  f32x4 acc[4][4] = {};
  for (int k0 = 0; k0 < K; k0 += 64) {
#pragma unroll
    for (int j = 0; j < 4; j++) {
      async16(alds + j * 512, aptr + k0 + (long)j * 8 * K);
      async16(blds + j * 512, bptr + k0 + (long)j * 8 * K);
    }
    __syncthreads();
    half8 a[2][4], b[2][4];
#pragma unroll
    for (int kk = 0; kk < 2; kk++)
#pragma unroll
      for (int mf = 0; mf < 4; mf++) {
        a[kk][mf] = *(const half8*)&As[(wm * 64 + mf * 16 + lr) * 64 +
                                       (((kk * 4 + lg) ^ (lr & 7)) * 8)];
        b[kk][mf] = *(const half8*)&Bs[(wn * 64 + mf * 16 + lr) * 64 +
                                       (((kk * 4 + lg) ^ (lr & 7)) * 8)];
      }
#pragma unroll
    for (int kk = 0; kk < 2; kk++)
#pragma unroll
      for (int mf = 0; mf < 4; mf++)
#pragma unroll
        for (int nf = 0; nf < 4; nf++)
          acc[mf][nf] =
              __builtin_amdgcn_mfma_f32_16x16x32_f16(a[kk][mf], b[kk][nf], acc[mf][nf], 0, 0, 0);
    __syncthreads();
  }

#pragma unroll
  for (int mf = 0; mf < 4; mf++) {
#pragma unroll
    for (int nf = 0; nf < 4; nf++) {
      int rbase = row0 + wm * 64 + mf * 16 + lg * 4;  // s
      int col = col0 + wn * 64 + nf * 16 + lr;
      if (col0 < 4096) {  // Q frag-tiled (pre-rope)
        int h = col >> 7, d = col & 127;
        long off = ((long)((h * 128 + (rbase >> 4)) * 4 + (d >> 5))) * 512 +
                   ((d >> 3) & 3) * 128 + (rbase & 15) * 8 + (d & 7);
#pragma unroll
        for (int i = 0; i < 4; i++) Qt[off + i * 8] = (_Float16)acc[mf][nf][i];
      } else if (col0 < 5120) {  // K frag-tiled (pre-rope)
        int gc = col - 4096;
        int g = gc >> 7, d = gc & 127;
        long off = ((long)((g * 128 + (rbase >> 4)) * 4 + (d >> 5))) * 512 +
                   ((d >> 3) & 3) * 128 + (rbase & 15) * 8 + (d & 7);
#pragma unroll
        for (int i = 0; i < 4; i++) Kt[off + i * 8] = (_Float16)acc[mf][nf][i];
      } else {  // V PV-fragment layout
        int gc = col - 5120;
        int gq = gc >> 7, d = gc & 127;
        int dt = d >> 4, lrr = d & 15;
        int kvb = rbase >> 5, lgv = (rbase >> 3) & 3, j = rbase & 7;
        half4 v;
#pragma unroll
        for (int i = 0; i < 4; i++) v[i] = (_Float16)acc[mf][nf][i];
        long off = ((long)(gq * 64 + kvb) * 8 + dt) * 512 + (lgv * 16 + lrr) * 8 + j;
        *(half4*)&Vt[off] = v;
      }
    }
  }
}

// ---------- O-projection GEMM: [2048][4096] f16 @ [4096][4096]^T -> f32 out ----------
__global__ __launch_bounds__(256, 3) void gemm_out(
    const _Float16* __restrict__ A, const _Float16* __restrict__ Bt,
    float* __restrict__ C) {
  __shared__ _Float16 As[128 * 64];
  __shared__ _Float16 Bs[128 * 64];
  const int K = 4096;
  const int tid = threadIdx.x, lane = tid & 63, wid = tid >> 6;
  const int row0 = blockIdx.y * 128;
  const int col0 = blockIdx.x * 128;
  const int wm = wid >> 1, wn = wid & 1;
  const int lr = lane & 15, lg = lane >> 4;

  const int scol = ((lane & 7) ^ ((lane >> 3) & 7)) * 8;
  const _Float16* aptr = A + (long)(row0 + wid * 32 + (lane >> 3)) * K + scol;
  const _Float16* bptr = Bt + (long)(col0 + wid * 32 + (lane >> 3)) * K + scol;
  _Float16* alds = As + (wid * 4) * 512;
  _Float16* blds = Bs + (wid * 4) * 512;

  f32x4 acc[4][4] = {};
  for (int k0 = 0; k0 < K; k0 += 64) {
#pragma unroll
    for (int j = 0; j < 4; j++) {
      async16(alds + j * 512, aptr + k0 + (long)j * 8 * K);
      async16(blds + j * 512, bptr + k0 + (long)j * 8 * K);
    }
    __syncthreads();
    half8 a[2][4], b[2][4];
#pragma unroll
    for (int kk = 0; kk < 2; kk++)
#pragma unroll
      for (int mf = 0; mf < 4; mf++) {
        a[kk][mf] = *(const half8*)&As[(wm * 64 + mf * 16 + lr) * 64 +
                                       (((kk * 4 + lg) ^ (lr & 7)) * 8)];
        b[kk][mf] = *(const half8*)&Bs[(wn * 64 + mf * 16 + lr) * 64 +
                                       (((kk * 4 + lg) ^ (lr & 7)) * 8)];
      }
#pragma unroll
    for (int kk = 0; kk < 2; kk++)
#pragma unroll
      for (int mf = 0; mf < 4; mf++)
#pragma unroll
        for (int nf = 0; nf < 4; nf++)
          acc[mf][nf] =
              __builtin_amdgcn_mfma_f32_16x16x32_f16(a[kk][mf], b[kk][nf], acc[mf][nf], 0, 0, 0);
    __syncthreads();
  }
#pragma unroll
  for (int mf = 0; mf < 4; mf++)
#pragma unroll
    for (int nf = 0; nf < 4; nf++) {
      int rbase = row0 + wm * 64 + mf * 16 + lg * 4;
      int col = col0 + wn * 64 + nf * 16 + lr;
#pragma unroll
      for (int i = 0; i < 4; i++)
        C[(long)(rbase + i) * 4096 + col] = acc[mf][nf][i];
    }
}

// ---------- fused: causal GQA attention (bid<1024) + wo^T transpose (bid>=1024) ----------
// attn blocks dispatch first (long pole); transpose blocks (pure HBM) fill in and
// hide under attn's compute. WoT region (=wq^T region) is dead after gemm_qkv.
__global__ __launch_bounds__(256, 3) void attn_wo_kernel(
    const _Float16* __restrict__ Qt, const _Float16* __restrict__ Kt,
    const _Float16* __restrict__ Vt, _Float16* __restrict__ O,
    const float* __restrict__ cosb, const float* __restrict__ sinb,
    const float* __restrict__ wo, _Float16* __restrict__ WoT) {
  __shared__ __align__(16) char smem[36864];  // attn: 36864B; transpose tile: 18688B
  const int tid = threadIdx.x;
  const int bid = blockIdx.x;  // 1024 attn + 4096 transpose

  if (bid >= 1024) {  // ---- wo^T: [4096][4096] f32 -> f16 [4096][4096]
    int tt = bid - 1024;
    transpose_tile(wo, WoT, 4096, 4096, tt & 63, tt >> 6, (float(*)[73])smem, tid);
    return;
  }

  _Float16* Kb = (_Float16*)smem;          // [2][4096]
  _Float16* Vb = (_Float16*)(smem + 16384);  // [2][4096]
  _Float16* Pb = (_Float16*)(smem + 32768) + (tid >> 6) * 512;  // per-wave [512]

  const int lane = tid & 63;
  const int wid = tid >> 6;
  const int g = bid & 7;
  const int qidx = bid >> 3;
  const int qt16 = (qidx < 64) ? (2 * qidx) : (2 * (127 - qidx) + 1);
  const int h = g * 4 + wid;
  const int qrow0 = qt16 * 16;
  const int ntiles = (qrow0 + 47) >> 5;
  const int lr = lane & 15;
  const int lg = lane >> 4;

  // Q fragments + fused RoPE (rotate-half partner: fragment t <-> t+2, same lane)
  half8 qf[4];
  {
    const _Float16* qp = Qt + ((long)(h * 128 + qt16) * 4) * 512 + lane * 8;
#pragma unroll
    for (int t = 0; t < 4; t++) qf[t] = *(const half8*)(qp + t * 512);
    int s = qrow0 + lr;
#pragma unroll
    for (int t = 0; t < 2; t++) {
      const float* cp = cosb + s * 128 + t * 32 + lg * 8;
      const float* sp = sinb + s * 128 + t * 32 + lg * 8;
#pragma unroll
      for (int j = 0; j < 8; j++) {
        float c = cp[j], sn = sp[j];
        float lo = (float)qf[t][j], hi = (float)qf[t + 2][j];
        qf[t][j]     = (_Float16)(lo * c - hi * sn);
        qf[t + 2][j] = (_Float16)(hi * c + lo * sn);
      }
    }
  }

  const _Float16* kgb = Kt + (long)g * 128 * 2048 + lane * 8;
  const _Float16* vgb = Vt + (long)g * 64 * 4096 + lane * 8;

  {
    async16(&Kb[(2 * wid) * 512], kgb + (2 * wid) * 512);
    async16(&Kb[(2 * wid + 1) * 512], kgb + (2 * wid + 1) * 512);
    async16(&Vb[(2 * wid) * 512], vgb + (2 * wid) * 512);
    async16(&Vb[(2 * wid + 1) * 512], vgb + (2 * wid + 1) * 512);
  }
  __syncthreads();

  f32x4 oacc[8] = {};
  float mrow[4] = {-1e30f, -1e30f, -1e30f, -1e30f};
  float lsum[4] = {0.f, 0.f, 0.f, 0.f};

  for (int t = 0; t < ntiles; t++) {
    const int kb = t * 32;
    const int cur = t & 1;
    if (t + 1 < ntiles) {
      const _Float16* ks = kgb + (long)(t + 1) * 4096;
      const _Float16* vs = vgb + (long)(t + 1) * 4096;
      async16(&Kb[(cur ^ 1) * 4096 + (2 * wid) * 512], ks + (2 * wid) * 512);
      async16(&Kb[(cur ^ 1) * 4096 + (2 * wid + 1) * 512], ks + (2 * wid + 1) * 512);
      async16(&Vb[(cur ^ 1) * 4096 + (2 * wid) * 512], vs + (2 * wid) * 512);
      async16(&Vb[(cur ^ 1) * 4096 + (2 * wid + 1) * 512], vs + (2 * wid + 1) * 512);
    }

    half8 kf[8];
#pragma unroll
    for (int c = 0; c < 8; c++)
      kf[c] = *(const half8*)&Kb[cur * 4096 + c * 512 + lane * 8];
    half8 vf[8];
#pragma unroll
    for (int dt = 0; dt < 8; dt++)
      vf[dt] = *(const half8*)&Vb[cur * 4096 + dt * 512 + lane * 8];

    f32x4 sacc[2] = {};
    __builtin_amdgcn_s_setprio(1);
#pragma unroll
    for (int s = 0; s < 2; s++)
#pragma unroll
      for (int t2 = 0; t2 < 4; t2++)
        sacc[s] = __builtin_amdgcn_mfma_f32_16x16x32_f16(qf[t2], kf[s * 4 + t2], sacc[s], 0, 0, 0);
    __builtin_amdgcn_s_setprio(0);

    float mx[4];
    bool grow = false;
#pragma unroll
    for (int i = 0; i < 4; i++) {
      int qrow = qrow0 + lg * 4 + i;
      float s0 = sacc[0][i] * SCALE_QK;
      float s1 = sacc[1][i] * SCALE_QK;
      if (kb + lr > qrow) s0 = -1e30f;
      if (kb + 16 + lr > qrow) s1 = -1e30f;
      sacc[0][i] = s0; sacc[1][i] = s1;
      mx[i] = fmaxf(s0, s1);
      grow |= (mx[i] > mrow[i] + 4.0f);
    }
    if (__any((int)grow)) {
#pragma unroll
      for (int i = 0; i < 4; i++) {
        float m = mx[i];
        m = fmaxf(m, __shfl_xor(m, 1));
        m = fmaxf(m, __shfl_xor(m, 2));
        m = fmaxf(m, __shfl_xor(m, 4));
        m = fmaxf(m, __shfl_xor(m, 8));
        float mn = fmaxf(mrow[i], m);
        float scl = __expf(mrow[i] - mn);
        mrow[i] = mn;
        lsum[i] *= scl;
#pragma unroll
        for (int dt = 0; dt < 8; dt++) oacc[dt][i] *= scl;
      }
    }
    float p[2][4];
#pragma unroll
    for (int i = 0; i < 4; i++) {
      p[0][i] = __expf(sacc[0][i] - mrow[i]);
      p[1][i] = __expf(sacc[1][i] - mrow[i]);
      lsum[i] += p[0][i] + p[1][i];
    }

#pragma unroll
    for (int sub = 0; sub < 2; sub++)
#pragma unroll
      for (int i = 0; i < 4; i++)
        Pb[(lg * 4 + i) * 32 + sub * 16 + lr] = (_Float16)p[sub][i];
    half8 pa = *(const half8*)&Pb[lr * 32 + lg * 8];

    __builtin_amdgcn_s_setprio(1);
#pragma unroll
    for (int dt = 0; dt < 8; dt++)
      oacc[dt] = __builtin_amdgcn_mfma_f32_16x16x32_f16(pa, vf[dt], oacc[dt], 0, 0, 0);
    __builtin_amdgcn_s_setprio(0);

    __syncthreads();
  }

#pragma unroll
  for (int i = 0; i < 4; i++) {
    float t2 = lsum[i];
    t2 += __shfl_xor(t2, 1);
    t2 += __shfl_xor(t2, 2);
    t2 += __shfl_xor(t2, 4);
    t2 += __shfl_xor(t2, 8);
    lsum[i] = t2;
  }
#pragma unroll
  for (int dt = 0; dt < 8; dt++) {
#pragma unroll
    for (int i = 0; i < 4; i++) {
      float o = oacc[dt][i] / lsum[i];
      O[(long)(qrow0 + lg * 4 + i) * HID_DIM + h * HEAD_DIM + dt * 16 + lr] = (_Float16)o;
    }
  }
}

extern "C" void kernel_launch(void* const* d_in, const int* in_sizes, int n_in,
                              void* d_out, int out_size, void* d_ws, size_t ws_size,
                              hipStream_t stream) {
  const float* x    = (const float*)d_in[0];
  const float* cosb = (const float*)d_in[1];
  const float* sinb = (const float*)d_in[2];
  // d_in[3] = attn_mask: pure causal, implemented in-kernel
  const float* wq = (const float*)d_in[4];
  const float* wk = (const float*)d_in[5];
  const float* wv = (const float*)d_in[6];
  const float* wo = (const float*)d_in[7];
  float* out = (float*)d_out;

  char* ws = (char*)d_ws;
  _Float16* Xh    = (_Float16*)(ws);                        // [0,16M): X f16; later Oattn
  _Float16* Oattn = Xh;
  _Float16* Qt    = (_Float16*)(ws + (size_t)(16 << 20));   // [16,32M): Q frag-tiled (pre-rope)
  _Float16* Kt    = (_Float16*)(ws + (size_t)(32 << 20));   // [32,36M): K frag-tiled
  _Float16* Vt    = (_Float16*)(ws + (size_t)(36 << 20));   // [36,40M): V PV-tiled
  _Float16* WqT   = (_Float16*)(ws + (size_t)(40 << 20));   // [40,72M): wq^T, later wo^T
  _Float16* WoT   = WqT;
  _Float16* WkvT  = (_Float16*)d_out;                       // 16MB scratch in d_out
  // peak ws usage: 72 MiB

  dim3 b256(256);

  // merged prep: X->f16 + wq^T + wk^T + wv^T (one dispatch, 10240 blocks)
  prep_kernel<<<dim3(10240), b256, 0, stream>>>(x, Xh, wq, WqT, wk, wv, WkvT);

  // merged QKV projection (N=6144, 768 blocks = 3/CU)
  gemm_qkv<<<dim3(6144 / 128, S_LEN / 128), b256, 0, stream>>>(Xh, WqT, WkvT, Qt, Kt, Vt);

  // RoPE in place on tiled K only (Q roped inside attn)
  rope_tiled<N_KV><<<dim3(N_KV * 16384 / 256), b256, 0, stream>>>(Kt, cosb, sinb);

  // fused: causal GQA attention (+Q-RoPE) -> Oattn, with wo^T hidden underneath
  attn_wo_kernel<<<dim3(1024 + 4096), b256, 0, stream>>>(Qt, Kt, Vt, Oattn, cosb, sinb, wo, WoT);

  // out = Oattn @ Wo (f32)
  gemm_out<<<dim3(4096 / 128, S_LEN / 128), b256, 0, stream>>>(Oattn, WoT, out);
}

// Round 10
// 290.605 us; speedup vs baseline: 1.1631x; 1.0211x over previous
//
#include <hip/hip_runtime.h>
#include <hip/hip_bf16.h>
#include <hip/hip_fp16.h>

typedef _Float16 half8 __attribute__((ext_vector_type(8)));
typedef _Float16 half4 __attribute__((ext_vector_type(4)));
typedef float f32x4 __attribute__((ext_vector_type(4)));
typedef unsigned int u32;

#define S_LEN 2048
#define HID_DIM 4096
#define N_HEADS 32
#define N_KV 8
#define HEAD_DIM 128
#define SCALE_QK 0.08838834764831845f

// ---------- async global->LDS (16B per lane, wave-uniform LDS base) ----------
__device__ __forceinline__ void async16(void* lds, const void* gptr) {
  __builtin_amdgcn_global_load_lds(
      (const __attribute__((address_space(1))) u32*)gptr,
      (__attribute__((address_space(3))) u32*)lds, 16, 0, 0);
}

// ---------- 64x64 transpose tile body (f32 [R][C] -> f16 [C][R]) ----------
__device__ __forceinline__ void transpose_tile(const float* __restrict__ src,
                                               _Float16* __restrict__ dst, int R, int C,
                                               int bx, int by, float (*tile)[73], int t) {
  {
    const int c4 = (t & 15) * 4;
    const int r0 = t >> 4;  // 0..15
#pragma unroll
    for (int i = 0; i < 4; i++) {
      int r = r0 + 16 * i;
      float4 v = *(const float4*)&src[(long)(by * 64 + r) * C + bx * 64 + c4];
      tile[r][c4] = v.x; tile[r][c4 + 1] = v.y; tile[r][c4 + 2] = v.z; tile[r][c4 + 3] = v.w;
    }
  }
  __syncthreads();
  const int kc = t & 7;
  const int n0 = t >> 3;  // 0..31
#pragma unroll
  for (int p = 0; p < 2; p++) {
    int n = n0 + 32 * p;
    half8 o;
#pragma unroll
    for (int j = 0; j < 8; j++) o[j] = (_Float16)tile[kc * 8 + j][n];
    *(half8*)&dst[(long)(bx * 64 + n) * R + by * 64 + kc * 8] = o;
  }
}

// ---------- merged prep: X conversion + wq^T + wk^T + wv^T in ONE dispatch ----------
__global__ void prep_kernel(const float* __restrict__ x, _Float16* __restrict__ Xh,
                            const float* __restrict__ wq, _Float16* __restrict__ WqT,
                            const float* __restrict__ wk, const float* __restrict__ wv,
                            _Float16* __restrict__ WkvT) {
  __shared__ float tile[64][73];
  const int bid = blockIdx.x;
  const int t = threadIdx.x;
  if (bid < 4096) {  // conv: 4096*256 == S*HID/8 exactly
    int i = bid * 256 + t;
    float4 a = ((const float4*)x)[2 * i];
    float4 b = ((const float4*)x)[2 * i + 1];
    half8 h;
    h[0] = (_Float16)a.x; h[1] = (_Float16)a.y; h[2] = (_Float16)a.z; h[3] = (_Float16)a.w;
    h[4] = (_Float16)b.x; h[5] = (_Float16)b.y; h[6] = (_Float16)b.z; h[7] = (_Float16)b.w;
    ((half8*)Xh)[i] = h;
  } else if (bid < 8192) {  // wq^T
    int tt = bid - 4096;
    transpose_tile(wq, WqT, 4096, 4096, tt & 63, tt >> 6, tile, t);
  } else if (bid < 9216) {  // wk^T
    int tt = bid - 8192;
    transpose_tile(wk, WkvT, 4096, 1024, tt & 15, tt >> 4, tile, t);
  } else {  // wv^T
    int tt = bid - 9216;
    transpose_tile(wv, WkvT + (size_t)1024 * 4096, 4096, 1024, tt & 15, tt >> 4, tile, t);
  }
}

// ---------- merged QKV GEMM: [2048][4096] @ [6144][4096]^T, BK=64, swizzled LDS ----------
// Q frag-tiled pre-rope; K frag-tiled WITH ROPE FUSED (cross-wave pair exchange
// through LDS overlay); V PV-fragment layout.
__global__ __launch_bounds__(256, 3) void gemm_qkv(
    const _Float16* __restrict__ A, const _Float16* __restrict__ BtQ,
    const _Float16* __restrict__ BtKV, _Float16* __restrict__ Qt,
    _Float16* __restrict__ Kt, _Float16* __restrict__ Vt,
    const float* __restrict__ cosb, const float* __restrict__ sinb) {
  __shared__ __align__(16) char smem[34816];  // As 16K | Bs 16K; rope overlay 128x68 f32
  _Float16* As = (_Float16*)smem;
  _Float16* Bs = (_Float16*)(smem + 16384);
  const int K = 4096;
  const int tid = threadIdx.x, lane = tid & 63, wid = tid >> 6;
  const int row0 = blockIdx.y * 128;
  const int col0 = blockIdx.x * 128;
  const int wm = wid >> 1, wn = wid & 1;
  const int lr = lane & 15, lg = lane >> 4;

  const _Float16* bbase = (col0 < 4096) ? (BtQ + (long)col0 * K)
                                        : (BtKV + (long)(col0 - 4096) * K);
  const int scol = ((lane & 7) ^ ((lane >> 3) & 7)) * 8;
  const _Float16* aptr = A + (long)(row0 + wid * 32 + (lane >> 3)) * K + scol;
  const _Float16* bptr = bbase + (long)(wid * 32 + (lane >> 3)) * K + scol;
  _Float16* alds = As + (wid * 4) * 512;
  _Float16* blds = Bs + (wid * 4) * 512;

  f32x4 acc[4][4] = {};
  for (int k0 = 0; k0 < K; k0 += 64) {
#pragma unroll
    for (int j = 0; j < 4; j++) {
      async16(alds + j * 512, aptr + k0 + (long)j * 8 * K);
      async16(blds + j * 512, bptr + k0 + (long)j * 8 * K);
    }
    __syncthreads();
    half8 a[2][4], b[2][4];
#pragma unroll
    for (int kk = 0; kk < 2; kk++)
#pragma unroll
      for (int mf = 0; mf < 4; mf++) {
        a[kk][mf] = *(const half8*)&As[(wm * 64 + mf * 16 + lr) * 64 +
                                       (((kk * 4 + lg) ^ (lr & 7)) * 8)];
        b[kk][mf] = *(const half8*)&Bs[(wn * 64 + mf * 16 + lr) * 64 +
                                       (((kk * 4 + lg) ^ (lr & 7)) * 8)];
      }
#pragma unroll
    for (int kk = 0; kk < 2; kk++)
#pragma unroll
      for (int mf = 0; mf < 4; mf++)
#pragma unroll
        for (int nf = 0; nf < 4; nf++)
          acc[mf][nf] =
              __builtin_amdgcn_mfma_f32_16x16x32_f16(a[kk][mf], b[kk][nf], acc[mf][nf], 0, 0, 0);
    __syncthreads();
  }

  if (col0 < 4096) {  // ---- Q frag-tiled (pre-rope)
#pragma unroll
    for (int mf = 0; mf < 4; mf++)
#pragma unroll
      for (int nf = 0; nf < 4; nf++) {
        int rbase = row0 + wm * 64 + mf * 16 + lg * 4;
        int col = col0 + wn * 64 + nf * 16 + lr;
        int h = col >> 7, d = col & 127;
        long off = ((long)((h * 128 + (rbase >> 4)) * 4 + (d >> 5))) * 512 +
                   ((d >> 3) & 3) * 128 + (rbase & 15) * 8 + (d & 7);
#pragma unroll
        for (int i = 0; i < 4; i++) Qt[off + i * 8] = (_Float16)acc[mf][nf][i];
      }
  } else if (col0 < 5120) {  // ---- K frag-tiled + fused RoPE
    const int g = (col0 - 4096) >> 7;
    float* fl = (float*)smem;  // [128 s_local][stride 68] f32 (2-way banks)
    if (wn == 1) {             // d_hi = 64 + nf*16+lr -> stash for partner wave
#pragma unroll
      for (int mf = 0; mf < 4; mf++)
#pragma unroll
        for (int nf = 0; nf < 4; nf++)
#pragma unroll
          for (int i = 0; i < 4; i++)
            fl[(wm * 64 + mf * 16 + lg * 4 + i) * 68 + nf * 16 + lr] = acc[mf][nf][i];
    }
    __syncthreads();
    if (wn == 0) {  // holds d_lo = nf*16+lr; writes BOTH halves roped
#pragma unroll
      for (int mf = 0; mf < 4; mf++)
#pragma unroll
        for (int nf = 0; nf < 4; nf++)
#pragma unroll
          for (int i = 0; i < 4; i++) {
            int s_local = wm * 64 + mf * 16 + lg * 4 + i;
            int d = nf * 16 + lr;
            int s_glob = row0 + s_local;
            float lo = acc[mf][nf][i];
            float hi = fl[s_local * 68 + d];
            float c = cosb[s_glob * 128 + d];
            float sn = sinb[s_glob * 128 + d];
            long off = ((long)((g * 128 + (s_glob >> 4)) * 4 + (d >> 5))) * 512 +
                       ((d >> 3) & 3) * 128 + (s_glob & 15) * 8 + (d & 7);
            Kt[off] = (_Float16)(lo * c - hi * sn);
            Kt[off + 1024] = (_Float16)(hi * c + lo * sn);
          }
    }
  } else {  // ---- V PV-fragment layout
#pragma unroll
    for (int mf = 0; mf < 4; mf++)
#pragma unroll
      for (int nf = 0; nf < 4; nf++) {
        int rbase = row0 + wm * 64 + mf * 16 + lg * 4;
        int col = col0 + wn * 64 + nf * 16 + lr;
        int gc = col - 5120;
        int gq = gc >> 7, d = gc & 127;
        int dt = d >> 4, lrr = d & 15;
        int kvb = rbase >> 5, lgv = (rbase >> 3) & 3, j = rbase & 7;
        half4 v;
#pragma unroll
        for (int i = 0; i < 4; i++) v[i] = (_Float16)acc[mf][nf][i];
        long off = ((long)(gq * 64 + kvb) * 8 + dt) * 512 + (lgv * 16 + lrr) * 8 + j;
        *(half4*)&Vt[off] = v;
      }
  }
}

// ---------- O-projection GEMM: [2048][4096] f16 @ [4096][4096]^T -> f32 out ----------
__global__ __launch_bounds__(256, 3) void gemm_out(
    const _Float16* __restrict__ A, const _Float16* __restrict__ Bt,
    float* __restrict__ C) {
  __shared__ _Float16 As[128 * 64];
  __shared__ _Float16 Bs[128 * 64];
  const int K = 4096;
  const int tid = threadIdx.x, lane = tid & 63, wid = tid >> 6;
  const int row0 = blockIdx.y * 128;
  const int col0 = blockIdx.x * 128;
  const int wm = wid >> 1, wn = wid & 1;
  const int lr = lane & 15, lg = lane >> 4;

  const int scol = ((lane & 7) ^ ((lane >> 3) & 7)) * 8;
  const _Float16* aptr = A + (long)(row0 + wid * 32 + (lane >> 3)) * K + scol;
  const _Float16* bptr = Bt + (long)(col0 + wid * 32 + (lane >> 3)) * K + scol;
  _Float16* alds = As + (wid * 4) * 512;
  _Float16* blds = Bs + (wid * 4) * 512;

  f32x4 acc[4][4] = {};
  for (int k0 = 0; k0 < K; k0 += 64) {
#pragma unroll
    for (int j = 0; j < 4; j++) {
      async16(alds + j * 512, aptr + k0 + (long)j * 8 * K);
      async16(blds + j * 512, bptr + k0 + (long)j * 8 * K);
    }
    __syncthreads();
    half8 a[2][4], b[2][4];
#pragma unroll
    for (int kk = 0; kk < 2; kk++)
#pragma unroll
      for (int mf = 0; mf < 4; mf++) {
        a[kk][mf] = *(const half8*)&As[(wm * 64 + mf * 16 + lr) * 64 +
                                       (((kk * 4 + lg) ^ (lr & 7)) * 8)];
        b[kk][mf] = *(const half8*)&Bs[(wn * 64 + mf * 16 + lr) * 64 +
                                       (((kk * 4 + lg) ^ (lr & 7)) * 8)];
      }
#pragma unroll
    for (int kk = 0; kk < 2; kk++)
#pragma unroll
      for (int mf = 0; mf < 4; mf++)
#pragma unroll
        for (int nf = 0; nf < 4; nf++)
          acc[mf][nf] =
              __builtin_amdgcn_mfma_f32_16x16x32_f16(a[kk][mf], b[kk][nf], acc[mf][nf], 0, 0, 0);
    __syncthreads();
  }
#pragma unroll
  for (int mf = 0; mf < 4; mf++)
#pragma unroll
    for (int nf = 0; nf < 4; nf++) {
      int rbase = row0 + wm * 64 + mf * 16 + lg * 4;
      int col = col0 + wn * 64 + nf * 16 + lr;
#pragma unroll
      for (int i = 0; i < 4; i++)
        C[(long)(rbase + i) * 4096 + col] = acc[mf][nf][i];
    }
}

// ---------- fused: causal GQA attention (bid<1024) + wo^T transpose (bid>=1024) ----------
__global__ __launch_bounds__(256, 3) void attn_wo_kernel(
    const _Float16* __restrict__ Qt, const _Float16* __restrict__ Kt,
    const _Float16* __restrict__ Vt, _Float16* __restrict__ O,
    const float* __restrict__ cosb, const float* __restrict__ sinb,
    const float* __restrict__ wo, _Float16* __restrict__ WoT) {
  __shared__ __align__(16) char smem[36864];
  const int tid = threadIdx.x;
  const int bid = blockIdx.x;  // 1024 attn + 4096 transpose

  if (bid >= 1024) {  // ---- wo^T
    int tt = bid - 1024;
    transpose_tile(wo, WoT, 4096, 4096, tt & 63, tt >> 6, (float(*)[73])smem, tid);
    return;
  }

  _Float16* Kb = (_Float16*)smem;            // [2][4096]
  _Float16* Vb = (_Float16*)(smem + 16384);  // [2][4096]
  _Float16* Pb = (_Float16*)(smem + 32768) + (tid >> 6) * 512;  // per-wave [512]

  const int lane = tid & 63;
  const int wid = tid >> 6;
  const int g = bid & 7;
  const int qidx = bid >> 3;
  const int qt16 = (qidx < 64) ? (2 * qidx) : (2 * (127 - qidx) + 1);
  const int h = g * 4 + wid;
  const int qrow0 = qt16 * 16;
  const int ntiles = (qrow0 + 47) >> 5;
  const int lr = lane & 15;
  const int lg = lane >> 4;

  // Q fragments + fused RoPE (rotate-half partner: fragment t <-> t+2, same lane)
  half8 qf[4];
  {
    const _Float16* qp = Qt + ((long)(h * 128 + qt16) * 4) * 512 + lane * 8;
#pragma unroll
    for (int t = 0; t < 4; t++) qf[t] = *(const half8*)(qp + t * 512);
    int s = qrow0 + lr;
#pragma unroll
    for (int t = 0; t < 2; t++) {
      const float* cp = cosb + s * 128 + t * 32 + lg * 8;
      const float* sp = sinb + s * 128 + t * 32 + lg * 8;
#pragma unroll
      for (int j = 0; j < 8; j++) {
        float c = cp[j], sn = sp[j];
        float lo = (float)qf[t][j], hi = (float)qf[t + 2][j];
        qf[t][j]     = (_Float16)(lo * c - hi * sn);
        qf[t + 2][j] = (_Float16)(hi * c + lo * sn);
      }
    }
  }

  const _Float16* kgb = Kt + (long)g * 128 * 2048 + lane * 8;
  const _Float16* vgb = Vt + (long)g * 64 * 4096 + lane * 8;

  {
    async16(&Kb[(2 * wid) * 512], kgb + (2 * wid) * 512);
    async16(&Kb[(2 * wid + 1) * 512], kgb + (2 * wid + 1) * 512);
    async16(&Vb[(2 * wid) * 512], vgb + (2 * wid) * 512);
    async16(&Vb[(2 * wid + 1) * 512], vgb + (2 * wid + 1) * 512);
  }
  __syncthreads();

  f32x4 oacc[8] = {};
  float mrow[4] = {-1e30f, -1e30f, -1e30f, -1e30f};
  float lsum[4] = {0.f, 0.f, 0.f, 0.f};

  for (int t = 0; t < ntiles; t++) {
    const int kb = t * 32;
    const int cur = t & 1;
    if (t + 1 < ntiles) {
      const _Float16* ks = kgb + (long)(t + 1) * 4096;
      const _Float16* vs = vgb + (long)(t + 1) * 4096;
      async16(&Kb[(cur ^ 1) * 4096 + (2 * wid) * 512], ks + (2 * wid) * 512);
      async16(&Kb[(cur ^ 1) * 4096 + (2 * wid + 1) * 512], ks + (2 * wid + 1) * 512);
      async16(&Vb[(cur ^ 1) * 4096 + (2 * wid) * 512], vs + (2 * wid) * 512);
      async16(&Vb[(cur ^ 1) * 4096 + (2 * wid + 1) * 512], vs + (2 * wid + 1) * 512);
    }

    half8 kf[8];
#pragma unroll
    for (int c = 0; c < 8; c++)
      kf[c] = *(const half8*)&Kb[cur * 4096 + c * 512 + lane * 8];
    half8 vf[8];
#pragma unroll
    for (int dt = 0; dt < 8; dt++)
      vf[dt] = *(const half8*)&Vb[cur * 4096 + dt * 512 + lane * 8];

    f32x4 sacc[2] = {};
    __builtin_amdgcn_s_setprio(1);
#pragma unroll
    for (int s = 0; s < 2; s++)
#pragma unroll
      for (int t2 = 0; t2 < 4; t2++)
        sacc[s] = __builtin_amdgcn_mfma_f32_16x16x32_f16(qf[t2], kf[s * 4 + t2], sacc[s], 0, 0, 0);
    __builtin_amdgcn_s_setprio(0);

#pragma unroll
    for (int i = 0; i < 4; i++) {
      sacc[0][i] *= SCALE_QK;
      sacc[1][i] *= SCALE_QK;
    }
    if (t == ntiles - 1) {  // only the last tile can touch the diagonal
#pragma unroll
      for (int i = 0; i < 4; i++) {
        int qrow = qrow0 + lg * 4 + i;
        if (kb + lr > qrow) sacc[0][i] = -1e30f;
        if (kb + 16 + lr > qrow) sacc[1][i] = -1e30f;
      }
    }
    float mx[4];
    bool grow = false;
#pragma unroll
    for (int i = 0; i < 4; i++) {
      mx[i] = fmaxf(sacc[0][i], sacc[1][i]);
      grow |= (mx[i] > mrow[i] + 4.0f);
    }
    if (__any((int)grow)) {
#pragma unroll
      for (int i = 0; i < 4; i++) {
        float m = mx[i];
        m = fmaxf(m, __shfl_xor(m, 1));
        m = fmaxf(m, __shfl_xor(m, 2));
        m = fmaxf(m, __shfl_xor(m, 4));
        m = fmaxf(m, __shfl_xor(m, 8));
        float mn = fmaxf(mrow[i], m);
        float scl = __expf(mrow[i] - mn);
        mrow[i] = mn;
        lsum[i] *= scl;
#pragma unroll
        for (int dt = 0; dt < 8; dt++) oacc[dt][i] *= scl;
      }
    }
    float p[2][4];
#pragma unroll
    for (int i = 0; i < 4; i++) {
      p[0][i] = __expf(sacc[0][i] - mrow[i]);
      p[1][i] = __expf(sacc[1][i] - mrow[i]);
      lsum[i] += p[0][i] + p[1][i];
    }

#pragma unroll
    for (int sub = 0; sub < 2; sub++)
#pragma unroll
      for (int i = 0; i < 4; i++)
        Pb[(lg * 4 + i) * 32 + sub * 16 + lr] = (_Float16)p[sub][i];
    half8 pa = *(const half8*)&Pb[lr * 32 + lg * 8];

    __builtin_amdgcn_s_setprio(1);
#pragma unroll
    for (int dt = 0; dt < 8; dt++)
      oacc[dt] = __builtin_amdgcn_mfma_f32_16x16x32_f16(pa, vf[dt], oacc[dt], 0, 0, 0);
    __builtin_amdgcn_s_setprio(0);

    __syncthreads();
  }

#pragma unroll
  for (int i = 0; i < 4; i++) {
    float t2 = lsum[i];
    t2 += __shfl_xor(t2, 1);
    t2 += __shfl_xor(t2, 2);
    t2 += __shfl_xor(t2, 4);
    t2 += __shfl_xor(t2, 8);
    lsum[i] = t2;
  }
#pragma unroll
  for (int dt = 0; dt < 8; dt++) {
#pragma unroll
    for (int i = 0; i < 4; i++) {
      float o = oacc[dt][i] / lsum[i];
      O[(long)(qrow0 + lg * 4 + i) * HID_DIM + h * HEAD_DIM + dt * 16 + lr] = (_Float16)o;
    }
  }
}

extern "C" void kernel_launch(void* const* d_in, const int* in_sizes, int n_in,
                              void* d_out, int out_size, void* d_ws, size_t ws_size,
                              hipStream_t stream) {
  const float* x    = (const float*)d_in[0];
  const float* cosb = (const float*)d_in[1];
  const float* sinb = (const float*)d_in[2];
  // d_in[3] = attn_mask: pure causal, implemented in-kernel
  const float* wq = (const float*)d_in[4];
  const float* wk = (const float*)d_in[5];
  const float* wv = (const float*)d_in[6];
  const float* wo = (const float*)d_in[7];
  float* out = (float*)d_out;

  char* ws = (char*)d_ws;
  _Float16* Xh    = (_Float16*)(ws);                        // [0,16M): X f16; later Oattn
  _Float16* Oattn = Xh;
  _Float16* Qt    = (_Float16*)(ws + (size_t)(16 << 20));   // [16,32M): Q frag-tiled (pre-rope)
  _Float16* Kt    = (_Float16*)(ws + (size_t)(32 << 20));   // [32,36M): K frag-tiled (roped)
  _Float16* Vt    = (_Float16*)(ws + (size_t)(36 << 20));   // [36,40M): V PV-tiled
  _Float16* WqT   = (_Float16*)(ws + (size_t)(40 << 20));   // [40,72M): wq^T, later wo^T
  _Float16* WoT   = WqT;
  _Float16* WkvT  = (_Float16*)d_out;                       // 16MB scratch in d_out
  // peak ws usage: 72 MiB

  dim3 b256(256);

  // merged prep: X->f16 + wq^T + wk^T + wv^T (one dispatch, 10240 blocks)
  prep_kernel<<<dim3(10240), b256, 0, stream>>>(x, Xh, wq, WqT, wk, wv, WkvT);

  // merged QKV projection (N=6144, 768 blocks = 3/CU), K-RoPE fused in epilogue
  gemm_qkv<<<dim3(6144 / 128, S_LEN / 128), b256, 0, stream>>>(Xh, WqT, WkvT, Qt, Kt, Vt,
                                                               cosb, sinb);

  // fused: causal GQA attention (+Q-RoPE) -> Oattn, with wo^T hidden underneath
  attn_wo_kernel<<<dim3(1024 + 4096), b256, 0, stream>>>(Qt, Kt, Vt, Oattn, cosb, sinb, wo, WoT);

  // out = Oattn @ Wo (f32)
  gemm_out<<<dim3(4096 / 128, S_LEN / 128), b256, 0, stream>>>(Oattn, WoT, out);
}